// Round 15
// baseline (3313.070 us; speedup 1.0000x reference)
//
#include <hip/hip_runtime.h>
#include <hip/hip_bf16.h>
#include <math.h>

// Problem constants
#define NL 12
#define NH 12
#define DM 768
#define DH 64
#define TT 512
#define NB 16
#define MR (NB*TT)      // 8192 rows
#define D3 (3*DM)       // 2304
#define D4 (4*DM)       // 3072

typedef __bf16 bf16_t;
typedef __attribute__((ext_vector_type(8))) __bf16 bf16x8;
typedef __attribute__((ext_vector_type(4))) __bf16 bf16x4;
typedef __attribute__((ext_vector_type(4))) float f32x4;
typedef __attribute__((ext_vector_type(16))) float f32x16;
typedef __attribute__((ext_vector_type(4))) unsigned int u32x4;

__device__ __forceinline__ void gload_lds16(const void* g, void* l) {
  __builtin_amdgcn_global_load_lds(
      (const __attribute__((address_space(1))) unsigned int*)g,
      (__attribute__((address_space(3))) unsigned int*)l,
      16, 0, 0);
}

__device__ __forceinline__ unsigned pkbf(float a, float b) {
  unsigned short ua = __builtin_bit_cast(unsigned short, (bf16_t)a);
  unsigned short ub = __builtin_bit_cast(unsigned short, (bf16_t)b);
  return (unsigned)ua | ((unsigned)ub << 16);
}

// ---------------- weight transpose + f32->bf16 into BLOCKED layout, 2 dispatches ----------------
template <int HALF>
__global__ __launch_bounds__(256) void transpose_half(
    const float* __restrict__ wqkv, const float* __restrict__ wo,
    const float* __restrict__ wfc, const float* __restrict__ wproj,
    bf16_t* __restrict__ qkvT, bf16_t* __restrict__ woT,
    bf16_t* __restrict__ fcT, bf16_t* __restrict__ projT,
    int l0, int per_layer_out) {
  const int lay = l0 + blockIdx.z;
  int bid = blockIdx.x;
  const float* in; bf16_t* out; int N;
  if (HALF == 0) {
    if (bid < 216) {
      in = wqkv + (size_t)lay * DM * D3;
      out = qkvT + (per_layer_out ? 0 : (size_t)lay * D3 * DM);
      N = D3;
    } else {
      bid -= 216;
      in = wo + (size_t)lay * DM * DM;
      out = woT + (per_layer_out ? 0 : (size_t)lay * DM * DM);
      N = DM;
    }
  } else {
    if (bid < 288) {
      in = wfc + (size_t)lay * DM * D4;
      out = fcT + (per_layer_out ? 0 : (size_t)lay * D4 * DM);
      N = D4;
    } else {
      bid -= 288;
      in = wproj + (size_t)lay * D4 * DM;
      out = projT + (per_layer_out ? 0 : (size_t)lay * DM * D4);
      N = DM;
    }
  }
  const int nx = N >> 7;
  const int n0 = (bid % nx) * 128, k0 = (bid / nx) * 64;
  __shared__ float tile[64][128];   // 32 KB
  const int t = threadIdx.x;
  const int rr = t >> 5, c4 = (t & 31) * 4;
  #pragma unroll
  for (int it = 0; it < 8; ++it) {
    const int row = rr + it * 8;
    f32x4 v = __builtin_nontemporal_load((const f32x4*)&in[(size_t)(k0 + row) * N + n0 + c4]);
    *(f32x4*)&tile[row][c4] = v;
  }
  __syncthreads();
  const int n = t >> 1, kh = t & 1;
  const int rg = (n0 & 255) + n;
  const int nb = n0 >> 8;
  const int nbN = N >> 8;
  const int x = rg & 7;
  bf16_t* base = out + (((size_t)(k0 >> 6) * nbN + nb) * 256 + rg) * 64 + kh * 32;
  #pragma unroll
  for (int p4 = 0; p4 < 4; ++p4) {
    const int c = (kh * 4 + p4) ^ x;      // source k-chunk for stored position
    bf16x8 o;
    #pragma unroll
    for (int j = 0; j < 8; ++j) o[j] = (bf16_t)tile[c * 8 + j][n];
    *(bf16x8*)(base + (p4 << 3)) = o;
  }
}

// ---------------- LayerNorm, one WAVE per row ----------------
// MODE 0: plain LN(x).  MODE 1: x += pa_z0 + pa_z1 (bf16 slabs), then LN.
// MODE 2: x = wte[id] + wpe[t] (embedding, layer 0), then LN.
template <int MODE>
__global__ __launch_bounds__(256) void ln_kernel(float* __restrict__ x,
                                                 const bf16_t* __restrict__ pa,
                                                 const float* __restrict__ w,
                                                 const float* __restrict__ b,
                                                 bf16_t* __restrict__ out,
                                                 const int* __restrict__ ids,
                                                 const float* __restrict__ wte,
                                                 const float* __restrict__ wpe) {
  const int lane = threadIdx.x & 63, wv = threadIdx.x >> 6;
  const int row = blockIdx.x * 4 + wv;
  float* xr = x + (size_t)row * DM;
  const int c = lane * 4;
  float4 v0, v1, v2;
  if (MODE == 2) {
    const int tt = row & (TT - 1);
    const int id = ids[row];
    const float* wt = wte + (size_t)id * DM;
    const float* wp = wpe + (size_t)tt * DM;
    #pragma unroll
    for (int i = 0; i < 3; ++i) {
      const int cc = c + i * 256;
      float4 a = *(const float4*)&wt[cc];
      float4 bb = *(const float4*)&wp[cc];
      a.x += bb.x; a.y += bb.y; a.z += bb.z; a.w += bb.w;
      float4& v = i == 0 ? v0 : (i == 1 ? v1 : v2);
      v = a;
      *(float4*)&xr[cc] = v;
    }
  } else {
    v0 = *(const float4*)&xr[c];
    v1 = *(const float4*)&xr[c + 256];
    v2 = *(const float4*)&xr[c + 512];
  }
  if (MODE == 1) {
    const bf16_t* p0 = pa + (size_t)row * DM;
    const bf16_t* p1 = pa + (size_t)MR * DM + (size_t)row * DM;
    #pragma unroll
    for (int i = 0; i < 3; ++i) {
      const int cc = c + i * 256;
      bf16x4 a = *(const bf16x4*)&p0[cc];
      bf16x4 bb = *(const bf16x4*)&p1[cc];
      float4& v = i == 0 ? v0 : (i == 1 ? v1 : v2);
      v.x += (float)a[0] + (float)bb[0];
      v.y += (float)a[1] + (float)bb[1];
      v.z += (float)a[2] + (float)bb[2];
      v.w += (float)a[3] + (float)bb[3];
      *(float4*)&xr[cc] = v;
    }
  }
  float s = v0.x + v0.y + v0.z + v0.w + v1.x + v1.y + v1.z + v1.w
          + v2.x + v2.y + v2.z + v2.w;
  #pragma unroll
  for (int off = 32; off > 0; off >>= 1) s += __shfl_xor(s, off);
  const float mean = s * (1.0f / DM);
  float q = 0.0f;
  q += (v0.x-mean)*(v0.x-mean) + (v0.y-mean)*(v0.y-mean) + (v0.z-mean)*(v0.z-mean) + (v0.w-mean)*(v0.w-mean);
  q += (v1.x-mean)*(v1.x-mean) + (v1.y-mean)*(v1.y-mean) + (v1.z-mean)*(v1.z-mean) + (v1.w-mean)*(v1.w-mean);
  q += (v2.x-mean)*(v2.x-mean) + (v2.y-mean)*(v2.y-mean) + (v2.z-mean)*(v2.z-mean) + (v2.w-mean)*(v2.w-mean);
  #pragma unroll
  for (int off = 32; off > 0; off >>= 1) q += __shfl_xor(q, off);
  const float rs = rsqrtf(q * (1.0f / DM) + 1e-5f);
  bf16_t* o = out + (size_t)row * DM;
  #pragma unroll
  for (int i = 0; i < 3; ++i) {
    const int cc = c + i * 256;
    float4 vv = i == 0 ? v0 : (i == 1 ? v1 : v2);
    float4 ww = *(const float4*)&w[cc];
    float4 bb = *(const float4*)&b[cc];
    bf16x4 ob;
    ob[0] = (bf16_t)((vv.x - mean) * rs * ww.x + bb.x);
    ob[1] = (bf16_t)((vv.y - mean) * rs * ww.y + bb.y);
    ob[2] = (bf16_t)((vv.z - mean) * rs * ww.z + bb.z);
    ob[3] = (bf16_t)((vv.w - mean) * rs * ww.w + bb.w);
    *(bf16x4*)&o[cc] = ob;
  }
}

// =====================================================================
// 128x128 GEMM, 4 waves (2Mx2N), BK=64, SINGLE-buffered 32 KB LDS.
// launch_bounds(256,4) -> 4 blocks/CU (needs <=128 VGPR): per-block duty
// cycle ~25%, so 4 resident blocks cover the staging drain fully (m114).
// Both A-halves kept in regs (af[2][..]) -> only 2 B reads, no re-read;
// 16 ds_read_b128 per tile. MM order preserves per-acc k-order (bitwise
// identical results). SPLITK>1: blockIdx.z covers k-range. EPI2/ATOM0 ->
// bf16 partial store (merged by LN).
// =====================================================================
#define OFF(MAT, H) ((((MAT)*2) + (H)) * 4096)

#define STAGE(MAT, H, T) do {                                                   \
    const int _r0 = tid >> 3, _r1 = _r0 + 32, _c = tid & 7;                     \
    if ((MAT) == 0) {                                                           \
      const bf16_t* _g0 = A + (size_t)(m0 + (H)*32 + (_r0 & 31)) * Kstride      \
              + (T)*64 + ((_c ^ (_r0 & 7)) << 3);                               \
      const bf16_t* _g1 = A + (size_t)(m0 + 64 + (H)*32 + (_r1 & 31)) * Kstride \
              + (T)*64 + ((_c ^ (_r1 & 7)) << 3);                               \
      gload_lds16(_g0, &lds[OFF(0, H) + (w << 9)]);                             \
      gload_lds16(_g1, &lds[OFF(0, H) + 2048 + (w << 9)]);                      \
    } else {                                                                    \
      const int _gr0 = nboff + (H)*32 + (_r0 & 31);                             \
      const int _gr1 = nboff + 64 + (H)*32 + (_r1 & 31);                        \
      const bf16_t* _bb = BTB + (((size_t)(T) * nbN + nb256) << 14);            \
      gload_lds16(_bb + (_gr0 << 6) + (_c << 3), &lds[OFF(1, H) + (w << 9)]);        \
      gload_lds16(_bb + (_gr1 << 6) + (_c << 3), &lds[OFF(1, H) + 2048 + (w << 9)]); \
    }                                                                           \
  } while (0)

#define RD_A(MH) do {                                                           \
    _Pragma("unroll") for (int _mf = 0; _mf < 2; ++_mf) {                       \
      const int _lr = wr * 32 + _mf * 16 + l15;                                 \
      const int _x = _lr & 7;                                                   \
      af[MH][_mf][0] = *(const bf16x8*)&lds[OFF(0,MH) + _lr*64 + ((l4 ^ _x) << 3)];      \
      af[MH][_mf][1] = *(const bf16x8*)&lds[OFF(0,MH) + _lr*64 + (((4+l4) ^ _x) << 3)];  \
    } } while (0)

#define RD_B(NH) do {                                                           \
    _Pragma("unroll") for (int _nf = 0; _nf < 2; ++_nf) {                       \
      const int _lr = wc * 32 + _nf * 16 + l15;                                 \
      const int _x = _lr & 7;                                                   \
      bfr[_nf][0] = *(const bf16x8*)&lds[OFF(1,NH) + _lr*64 + ((l4 ^ _x) << 3)];         \
      bfr[_nf][1] = *(const bf16x8*)&lds[OFF(1,NH) + _lr*64 + (((4+l4) ^ _x) << 3)];     \
    } } while (0)

#define MM(MH, NH) do {                                                         \
    __builtin_amdgcn_s_setprio(1);                                              \
    _Pragma("unroll") for (int _ks = 0; _ks < 2; ++_ks)                         \
      _Pragma("unroll") for (int _mf = 0; _mf < 2; ++_mf)                       \
        _Pragma("unroll") for (int _nf = 0; _nf < 2; ++_nf)                     \
          acc[(MH)*2+_mf][(NH)*2+_nf] = __builtin_amdgcn_mfma_f32_16x16x32_bf16(\
              af[MH][_mf][_ks], bfr[_nf][_ks], acc[(MH)*2+_mf][(NH)*2+_nf], 0,0,0); \
    __builtin_amdgcn_s_setprio(0);                                              \
  } while (0)

// EPI: 0 = +bias -> bf16 ; 1 = +bias, tanh-approx GELU -> bf16 ; 2 = resid (see above)
template <int EPI, int SPLITK, int ATOM>
__global__ __launch_bounds__(256, 4) void gemm8(const bf16_t* __restrict__ A,
                                                const bf16_t* __restrict__ BTB,
                                                const float* __restrict__ bias,
                                                bf16_t* __restrict__ outb,
                                                float* __restrict__ resid,
                                                int Ndim, int Kdim, int Kstride, int nbN) {
  __shared__ bf16_t lds[16384];   // 32 KB single-buffered -> 4 blocks/CU
  const int tid = threadIdx.x, lane = tid & 63, w = tid >> 6;
  const int wr = w >> 1, wc = w & 1;
  const int l15 = lane & 15, l4 = lane >> 4;
  const int zz = (SPLITK > 1) ? blockIdx.z : 0;
  A += (size_t)zz * Kdim;
  BTB += ((size_t)zz * (Kdim >> 6) * nbN) << 14;

  // T1: bijective XCD-aware tile swizzle (m204). All grids here are %8==0.
  const unsigned nwg = gridDim.x * gridDim.y;
  const unsigned orig = blockIdx.y * gridDim.x + blockIdx.x;
  const unsigned q8 = nwg >> 3;
  const unsigned wg = (orig & 7) * q8 + (orig >> 3);
  const int m0 = (int)(wg / gridDim.x) * 128;
  const int n0 = (int)(wg % gridDim.x) * 128;
  const int nb256 = n0 >> 8, nboff = n0 & 255;   // 128-aligned -> nboff in {0,128}
  const int nT = Kdim >> 6;

  f32x4 acc[4][4] = {};
  bf16x8 af[2][2][2], bfr[2][2];

  for (int t = 0; t < nT; ++t) {
    __syncthreads();                 // previous tile's reads complete
    STAGE(0, 0, t); STAGE(1, 0, t); STAGE(0, 1, t); STAGE(1, 1, t);
    __syncthreads();                 // vmcnt(0) drain -> tile visible (TLP covers)
    RD_A(0); RD_A(1); RD_B(0);
    MM(0, 0); MM(1, 0);
    RD_B(1);
    MM(0, 1); MM(1, 1);
  }

  // epilogue: wave tile 64x64; acc[i][j] -> rows i*16, cols j*16
  #pragma unroll
  for (int mf = 0; mf < 4; ++mf) {
    #pragma unroll
    for (int nf = 0; nf < 4; ++nf) {
      const int col = n0 + wc * 64 + nf * 16 + l15;
      const float bv = (SPLITK == 1 || zz == 0) ? bias[col] : 0.0f;
      #pragma unroll
      for (int r = 0; r < 4; ++r) {
        const int row = m0 + wr * 64 + mf * 16 + l4 * 4 + r;
        float v = acc[mf][nf][r] + bv;
        if (EPI == 1) {
          const float z2 = 1.5957692f * v + 0.07135481f * v * v * v;
          v = v / (1.0f + __expf(-z2));
        }
        if (EPI == 2) {
          if (SPLITK > 1 && ATOM == 0) {
            outb[(size_t)zz * MR * Ndim + (size_t)row * Ndim + col] = (bf16_t)v;
          } else if (SPLITK > 1) {
            unsafeAtomicAdd(&resid[(size_t)row * Ndim + col], v);
          } else {
            resid[(size_t)row * Ndim + col] += v;
          }
        } else {
          outb[(size_t)row * Ndim + col] = (bf16_t)v;
        }
      }
    }
  }
}

// ---------------- fused flash attention (unchanged) ----------------
__global__ __launch_bounds__(512, 4) void attn_kernel(const bf16_t* __restrict__ qkv,
                                                      bf16_t* __restrict__ y) {
  const int qt = blockIdx.x, hh = blockIdx.y, bb = blockIdx.z;
  const int tid = threadIdx.x, lane = tid & 63, w = tid >> 6;
  const int l31 = lane & 31, hiL = lane >> 5;

  __shared__ bf16_t smem[18432];
  bf16_t* Kbuf = smem;
  bf16_t* Vbuf = smem + 8192;

  const bf16_t* kb = qkv + (size_t)(bb * TT) * D3 + DM + hh * 64;
  const bf16_t* vb = qkv + (size_t)(bb * TT) * D3 + 2 * DM + hh * 64;

  const bf16_t* qptr = qkv + (size_t)(bb * TT + qt * 256 + w * 32 + l31) * D3 + hh * 64 + hiL * 8;
  bf16x8 qreg[4];
  #pragma unroll
  for (int ks = 0; ks < 4; ++ks) {
    bf16x8 v = *(const bf16x8*)(qptr + ks * 16);
    #pragma unroll
    for (int j = 0; j < 8; ++j) qreg[ks][j] = (bf16_t)((float)v[j] * 0.125f);
  }

  const int sr = tid >> 3, sc = tid & 7;
  #define ATTN_STAGE(KT, BUF)                                                     \
    {                                                                             \
      gload_lds16(kb + (size_t)((KT) * 64 + sr) * D3 + ((sc ^ (sr & 7)) * 8),     \
                  Kbuf + (BUF) * 4096 + (w << 9));                                \
      bf16x8 tv;                                                                  \
      _Pragma("unroll")                                                           \
      for (int j = 0; j < 8; ++j) tv[j] = vb[(size_t)((KT) * 64 + w * 8 + j) * D3 + lane]; \
      *(bf16x8*)&Vbuf[(BUF) * 4096 + lane * 64 + ((w ^ (lane & 7)) << 3)] = tv;   \
    }

  ATTN_STAGE(0, 0);

  f32x16 o0 = 0.0f, o1 = 0.0f;
  float m = -INFINITY, l = 0.0f;

  for (int kt = 0; kt < 8; ++kt) {
    __syncthreads();
    if (kt < 7) ATTN_STAGE(kt + 1, (kt + 1) & 1);

    const bf16_t* Kb = Kbuf + (kt & 1) * 4096;
    const bf16_t* Vb = Vbuf + (kt & 1) * 4096;

    f32x16 st0 = 0.0f, st1 = 0.0f;
    #pragma unroll
    for (int ks = 0; ks < 4; ++ks) {
      const int ch = (ks * 2 + hiL) ^ (l31 & 7);
      bf16x8 kf0 = *(const bf16x8*)&Kb[l31 * 64 + ch * 8];
      bf16x8 kf1 = *(const bf16x8*)&Kb[(32 + l31) * 64 + ch * 8];
      st0 = __builtin_amdgcn_mfma_f32_32x32x16_bf16(kf0, qreg[ks], st0, 0, 0, 0);
      st1 = __builtin_amdgcn_mfma_f32_32x32x16_bf16(kf1, qreg[ks], st1, 0, 0, 0);
    }

    float tm = fmaxf(st0[0], st1[0]);
    #pragma unroll
    for (int i = 1; i < 16; ++i) tm = fmaxf(tm, fmaxf(st0[i], st1[i]));
    tm = fmaxf(tm, __shfl_xor(tm, 32));
    const float mnew = fmaxf(m, tm);
    const float al = __expf(m - mnew);
    #pragma unroll
    for (int i = 0; i < 16; ++i) st0[i] = __expf(st0[i] - mnew);
    #pragma unroll
    for (int i = 0; i < 16; ++i) st1[i] = __expf(st1[i] - mnew);
    float ps = 0.0f;
    #pragma unroll
    for (int i = 0; i < 16; ++i) ps += st0[i] + st1[i];
    ps += __shfl_xor(ps, 32);
    l = l * al + ps;
    m = mnew;
    #pragma unroll
    for (int i = 0; i < 16; ++i) { o0[i] *= al; o1[i] *= al; }

    #pragma unroll
    for (int g = 0; g < 2; ++g) {
      unsigned u0, u1, u2, u3, u4, u5, u6, u7;
      if (g == 0) {
        u0 = pkbf(st0[0], st0[1]);   u1 = pkbf(st0[2], st0[3]);
        u2 = pkbf(st0[4], st0[5]);   u3 = pkbf(st0[6], st0[7]);
        u4 = pkbf(st0[8], st0[9]);   u5 = pkbf(st0[10], st0[11]);
        u6 = pkbf(st0[12], st0[13]); u7 = pkbf(st0[14], st0[15]);
      } else {
        u0 = pkbf(st1[0], st1[1]);   u1 = pkbf(st1[2], st1[3]);
        u2 = pkbf(st1[4], st1[5]);   u3 = pkbf(st1[6], st1[7]);
        u4 = pkbf(st1[8], st1[9]);   u5 = pkbf(st1[10], st1[11]);
        u6 = pkbf(st1[12], st1[13]); u7 = pkbf(st1[14], st1[15]);
      }
      #pragma unroll
      for (int ks2 = 0; ks2 < 2; ++ks2) {
        const unsigned a0 = ks2 ? u4 : u0, a1 = ks2 ? u5 : u1;
        const unsigned a2 = ks2 ? u6 : u2, a3 = ks2 ? u7 : u3;
        const unsigned own0 = hiL ? a2 : a0, own1 = hiL ? a3 : a1;
        const unsigned snd0 = hiL ? a0 : a2, snd1 = hiL ? a1 : a3;
        const unsigned rcv0 = (unsigned)__shfl_xor((int)snd0, 32);
        const unsigned rcv1 = (unsigned)__shfl_xor((int)snd1, 32);
        u32x4 fw;
        fw[0] = hiL ? rcv0 : own0;
        fw[1] = hiL ? rcv1 : own1;
        fw[2] = hiL ? own0 : rcv0;
        fw[3] = hiL ? own1 : rcv1;
        const bf16x8 pa = __builtin_bit_cast(bf16x8, fw);
        const int chv = (g * 4 + ks2 * 2 + hiL) ^ (l31 & 7);
        bf16x8 vf0 = *(const bf16x8*)&Vb[l31 * 64 + chv * 8];
        bf16x8 vf1 = *(const bf16x8*)&Vb[(32 + l31) * 64 + chv * 8];
        o0 = __builtin_amdgcn_mfma_f32_32x32x16_bf16(vf0, pa, o0, 0, 0, 0);
        o1 = __builtin_amdgcn_mfma_f32_32x32x16_bf16(vf1, pa, o1, 0, 0, 0);
      }
    }
  }

  __syncthreads();
  const float rl = 1.0f / l;
  bf16_t* Ob = smem;
  #pragma unroll
  for (int reg = 0; reg < 16; ++reg) {
    const int drow = (reg & 3) + 8 * (reg >> 2) + 4 * hiL;
    Ob[(w * 32 + l31) * 72 + drow]      = (bf16_t)(o0[reg] * rl);
    Ob[(w * 32 + l31) * 72 + 32 + drow] = (bf16_t)(o1[reg] * rl);
  }
  __syncthreads();
  const int qrow = tid >> 1, half = tid & 1;
  bf16_t* yp = y + (size_t)(bb * TT + qt * 256 + qrow) * DM + hh * 64 + half * 32;
  const bf16_t* obp = &Ob[qrow * 72 + half * 32];
  *(bf16x8*)(yp)      = *(const bf16x8*)(obp);
  *(bf16x8*)(yp + 8)  = *(const bf16x8*)(obp + 8);
  *(bf16x8*)(yp + 16) = *(const bf16x8*)(obp + 16);
  *(bf16x8*)(yp + 24) = *(const bf16x8*)(obp + 24);
  #undef ATTN_STAGE
}

// ---------------- final LN (CLS) + dense + tanh -> pooled (MERGE: + bf16 partials) ----------------
template <int MERGE>
__global__ __launch_bounds__(256) void pooled_kernel(const float* __restrict__ x,
                                                     const bf16_t* __restrict__ pa,
                                                     const float* __restrict__ lnw,
                                                     const float* __restrict__ lnb,
                                                     const float* __restrict__ dw,
                                                     const float* __restrict__ db,
                                                     float* __restrict__ pooled) {
  const int bb = blockIdx.y, tid = threadIdx.x;
  const int lane = tid & 63, wv = tid >> 6;
  const size_t rb = (size_t)(bb * TT) * DM;
  const float* xr = x + rb;
  float v0 = xr[tid], v1 = xr[tid + 256], v2 = xr[tid + 512];
  if (MERGE) {
    const bf16_t* p0 = pa + rb;
    const bf16_t* p1 = pa + (size_t)MR * DM + rb;
    v0 += (float)p0[tid]       + (float)p1[tid];
    v1 += (float)p0[tid + 256] + (float)p1[tid + 256];
    v2 += (float)p0[tid + 512] + (float)p1[tid + 512];
  }
  __shared__ float red[8];
  __shared__ float lx[DM];
  float s = v0 + v1 + v2;
  #pragma unroll
  for (int off = 32; off > 0; off >>= 1) s += __shfl_down(s, off);
  if (lane == 0) red[wv] = s;
  __syncthreads();
  const float mean = (red[0] + red[1] + red[2] + red[3]) * (1.0f / DM);
  const float d0 = v0 - mean, d1 = v1 - mean, d2 = v2 - mean;
  float q = d0 * d0 + d1 * d1 + d2 * d2;
  #pragma unroll
  for (int off = 32; off > 0; off >>= 1) q += __shfl_down(q, off);
  __syncthreads();
  if (lane == 0) red[wv] = q;
  __syncthreads();
  const float var = (red[0] + red[1] + red[2] + red[3]) * (1.0f / DM);
  const float rs = rsqrtf(var + 1e-5f);

  lx[tid]       = d0 * rs * lnw[tid] + lnb[tid];
  lx[tid + 256] = d1 * rs * lnw[tid + 256] + lnb[tid + 256];
  lx[tid + 512] = d2 * rs * lnw[tid + 512] + lnb[tid + 512];
  __syncthreads();

  const int j = blockIdx.x * 64 + (tid >> 2), sl = tid & 3;
  const int k0 = sl * 192;
  float acc = 0.0f;
  #pragma unroll 4
  for (int k = k0; k < k0 + 192; ++k) acc += lx[k] * dw[(size_t)k * DM + j];
  acc += __shfl_xor(acc, 1);
  acc += __shfl_xor(acc, 2);
  if (sl == 0) pooled[bb * DM + j] = tanhf(acc + db[j]);
}

// ---------------- logits ----------------
__global__ void logits_kernel(const float* __restrict__ pooled,
                              const float* __restrict__ hw,
                              const float* __restrict__ hb,
                              float* __restrict__ out) {
  const int tid = threadIdx.x;
  if (tid < 32) {
    const int bb = tid >> 1, c = tid & 1;
    float acc = hb[c];
    for (int k = 0; k < DM; ++k) acc += pooled[bb * DM + k] * hw[k * 2 + c];
    out[bb * 2 + c] = acc;
  }
}

extern "C" void kernel_launch(void* const* d_in, const int* in_sizes, int n_in,
                              void* d_out, int out_size, void* d_ws, size_t ws_size,
                              hipStream_t stream) {
  const int*   ids   = (const int*)d_in[0];
  const float* wte   = (const float*)d_in[3];
  const float* wpe   = (const float*)d_in[4];
  const float* ln1w  = (const float*)d_in[5];
  const float* ln1b  = (const float*)d_in[6];
  const float* wqkv  = (const float*)d_in[7];
  const float* bqkv  = (const float*)d_in[8];
  const float* wo    = (const float*)d_in[9];
  const float* bo    = (const float*)d_in[10];
  const float* ln2w  = (const float*)d_in[11];
  const float* ln2b  = (const float*)d_in[12];
  const float* wfc   = (const float*)d_in[13];
  const float* bfc   = (const float*)d_in[14];
  const float* wproj = (const float*)d_in[15];
  const float* bproj = (const float*)d_in[16];
  const float* lnfw  = (const float*)d_in[17];
  const float* lnfb  = (const float*)d_in[18];
  const float* dw    = (const float*)d_in[19];
  const float* db    = (const float*)d_in[20];
  const float* hw    = (const float*)d_in[21];
  const float* hb    = (const float*)d_in[22];
  float* out = (float*)d_out;

  const size_t NEED_FULLW = 308330496ULL;                 // base + 12-layer weights
  const size_t NEED_SLAB  = NEED_FULLW + 25165824ULL;     // + bf16 proj partial slab
  const int mode = ws_size >= NEED_SLAB ? 2 : (ws_size >= NEED_FULLW ? 1 : 0);
  const bool full = mode >= 1;
  const bool slab = mode == 2;

  char* ws = (char*)d_ws;
  size_t off = 0;
  auto alloc = [&](size_t bytes) -> void* {
    void* p = ws + off;
    off += (bytes + 255) & ~(size_t)255;
    return p;
  };
  float*  x      = (float*)alloc((size_t)MR * DM * 4);
  bf16_t* h      = (bf16_t*)alloc((size_t)MR * DM * 2);
  bf16_t* qkvb   = (bf16_t*)alloc((size_t)MR * D3 * 2);
  bf16_t* yb     = (bf16_t*)alloc((size_t)MR * DM * 2);
  bf16_t* ub     = (bf16_t*)alloc((size_t)MR * D4 * 2);
  float*  pooled = (float*)alloc((size_t)NB * DM * 4);
  const size_t wmul = full ? NL : 1;
  bf16_t* wqkvT  = (bf16_t*)alloc((size_t)D3 * DM * 2 * wmul);
  bf16_t* woT    = (bf16_t*)alloc((size_t)DM * DM * 2 * wmul);
  bf16_t* wfcT   = (bf16_t*)alloc((size_t)D4 * DM * 2 * wmul);
  bf16_t* wprojT = (bf16_t*)alloc((size_t)DM * D4 * 2 * wmul);
  bf16_t* slabP  = slab ? (bf16_t*)alloc((size_t)2 * MR * DM * 2) : nullptr;
  bf16_t* slabW  = (bf16_t*)ub;   // wo partials alias ub (25MB of 50MB; disjoint lifetime)

  if (full) {
    transpose_half<0><<<dim3(288, 1, NL), 256, 0, stream>>>(
        wqkv, wo, wfc, wproj, wqkvT, woT, wfcT, wprojT, 0, 0);
    transpose_half<1><<<dim3(576, 1, NL), 256, 0, stream>>>(
        wqkv, wo, wfc, wproj, wqkvT, woT, wfcT, wprojT, 0, 0);
  }

  for (int l = 0; l < NL; ++l) {
    if (!full) {
      transpose_half<0><<<dim3(288, 1, 1), 256, 0, stream>>>(
          wqkv, wo, wfc, wproj, wqkvT, woT, wfcT, wprojT, l, 1);
      transpose_half<1><<<dim3(576, 1, 1), 256, 0, stream>>>(
          wqkv, wo, wfc, wproj, wqkvT, woT, wfcT, wprojT, l, 1);
    }
    bf16_t* qkvT_l = wqkvT + (full ? (size_t)l * D3 * DM : 0);
    bf16_t* woT_l  = woT   + (full ? (size_t)l * DM * DM : 0);
    bf16_t* fcT_l  = wfcT  + (full ? (size_t)l * D4 * DM : 0);
    bf16_t* prT_l  = wprojT+ (full ? (size_t)l * DM * D4 : 0);

    // ln1: l==0 fuses the embedding; slab mode merges previous layer's proj partials
    if (l == 0)
      ln_kernel<2><<<MR / 4, 256, 0, stream>>>(x, nullptr, ln1w, ln1b, h, ids, wte, wpe);
    else if (slab)
      ln_kernel<1><<<MR / 4, 256, 0, stream>>>(x, slabP, ln1w + l * DM, ln1b + l * DM, h,
                                               nullptr, nullptr, nullptr);
    else
      ln_kernel<0><<<MR / 4, 256, 0, stream>>>(x, nullptr, ln1w + l * DM, ln1b + l * DM, h,
                                               nullptr, nullptr, nullptr);

    gemm8<0, 1, 1><<<dim3(D3 / 128, MR / 128, 1), 256, 0, stream>>>(
        h, qkvT_l, bqkv + (size_t)l * D3, qkvb, nullptr, D3, DM, DM, D3 / 256);
    attn_kernel<<<dim3(TT / 256, NH, NB), 512, 0, stream>>>(qkvb, yb);

    if (slab) {
      gemm8<2, 2, 0><<<dim3(DM / 128, MR / 128, 2), 256, 0, stream>>>(
          yb, woT_l, bo + (size_t)l * DM, slabW, nullptr, DM, DM / 2, DM, DM / 256);
      ln_kernel<1><<<MR / 4, 256, 0, stream>>>(x, slabW, ln2w + l * DM, ln2b + l * DM, h,
                                               nullptr, nullptr, nullptr);
    } else {
      gemm8<2, 2, 1><<<dim3(DM / 128, MR / 128, 2), 256, 0, stream>>>(
          yb, woT_l, bo + (size_t)l * DM, nullptr, x, DM, DM / 2, DM, DM / 256);
      ln_kernel<0><<<MR / 4, 256, 0, stream>>>(x, nullptr, ln2w + l * DM, ln2b + l * DM, h,
                                               nullptr, nullptr, nullptr);
    }

    gemm8<1, 1, 1><<<dim3(D4 / 128, MR / 128, 1), 256, 0, stream>>>(
        h, fcT_l, bfc + (size_t)l * D4, ub, nullptr, D4, DM, DM, D4 / 256);

    if (slab) {
      gemm8<2, 2, 0><<<dim3(DM / 128, MR / 128, 2), 256, 0, stream>>>(
          ub, prT_l, bproj + (size_t)l * DM, slabP, nullptr, DM, D4 / 2, D4, DM / 256);
    } else {
      gemm8<2, 2, 1><<<dim3(DM / 128, MR / 128, 2), 256, 0, stream>>>(
          ub, prT_l, bproj + (size_t)l * DM, nullptr, x, DM, D4 / 2, D4, DM / 256);
    }
  }

  if (slab)
    pooled_kernel<1><<<dim3(12, NB), 256, 0, stream>>>(x, slabP, lnfw, lnfb, dw, db, pooled);
  else
    pooled_kernel<0><<<dim3(12, NB), 256, 0, stream>>>(x, nullptr, lnfw, lnfb, dw, db, pooled);
  logits_kernel<<<1, 64, 0, stream>>>(pooled, hw, hb, out);
}

// Round 16
// 2779.803 us; speedup vs baseline: 1.1918x; 1.1918x over previous
//
#include <hip/hip_runtime.h>
#include <hip/hip_bf16.h>
#include <math.h>

// Problem constants
#define NL 12
#define NH 12
#define DM 768
#define DH 64
#define TT 512
#define NB 16
#define MR (NB*TT)      // 8192 rows
#define D3 (3*DM)       // 2304
#define D4 (4*DM)       // 3072

typedef __bf16 bf16_t;
typedef __attribute__((ext_vector_type(8))) __bf16 bf16x8;
typedef __attribute__((ext_vector_type(4))) __bf16 bf16x4;
typedef __attribute__((ext_vector_type(4))) float f32x4;
typedef __attribute__((ext_vector_type(16))) float f32x16;
typedef __attribute__((ext_vector_type(4))) unsigned int u32x4;

__device__ __forceinline__ void gload_lds16(const void* g, void* l) {
  __builtin_amdgcn_global_load_lds(
      (const __attribute__((address_space(1))) unsigned int*)g,
      (__attribute__((address_space(3))) unsigned int*)l,
      16, 0, 0);
}

__device__ __forceinline__ unsigned pkbf(float a, float b) {
  unsigned short ua = __builtin_bit_cast(unsigned short, (bf16_t)a);
  unsigned short ub = __builtin_bit_cast(unsigned short, (bf16_t)b);
  return (unsigned)ua | ((unsigned)ub << 16);
}

// ---------------- weight transpose + f32->bf16 into BLOCKED layout, 2 dispatches ----------------
template <int HALF>
__global__ __launch_bounds__(256) void transpose_half(
    const float* __restrict__ wqkv, const float* __restrict__ wo,
    const float* __restrict__ wfc, const float* __restrict__ wproj,
    bf16_t* __restrict__ qkvT, bf16_t* __restrict__ woT,
    bf16_t* __restrict__ fcT, bf16_t* __restrict__ projT,
    int l0, int per_layer_out) {
  const int lay = l0 + blockIdx.z;
  int bid = blockIdx.x;
  const float* in; bf16_t* out; int N;
  if (HALF == 0) {
    if (bid < 216) {
      in = wqkv + (size_t)lay * DM * D3;
      out = qkvT + (per_layer_out ? 0 : (size_t)lay * D3 * DM);
      N = D3;
    } else {
      bid -= 216;
      in = wo + (size_t)lay * DM * DM;
      out = woT + (per_layer_out ? 0 : (size_t)lay * DM * DM);
      N = DM;
    }
  } else {
    if (bid < 288) {
      in = wfc + (size_t)lay * DM * D4;
      out = fcT + (per_layer_out ? 0 : (size_t)lay * D4 * DM);
      N = D4;
    } else {
      bid -= 288;
      in = wproj + (size_t)lay * D4 * DM;
      out = projT + (per_layer_out ? 0 : (size_t)lay * DM * D4);
      N = DM;
    }
  }
  const int nx = N >> 7;
  const int n0 = (bid % nx) * 128, k0 = (bid / nx) * 64;
  __shared__ float tile[64][128];   // 32 KB
  const int t = threadIdx.x;
  const int rr = t >> 5, c4 = (t & 31) * 4;
  #pragma unroll
  for (int it = 0; it < 8; ++it) {
    const int row = rr + it * 8;
    f32x4 v = __builtin_nontemporal_load((const f32x4*)&in[(size_t)(k0 + row) * N + n0 + c4]);
    *(f32x4*)&tile[row][c4] = v;
  }
  __syncthreads();
  const int n = t >> 1, kh = t & 1;
  const int rg = (n0 & 255) + n;
  const int nb = n0 >> 8;
  const int nbN = N >> 8;
  const int x = rg & 7;
  bf16_t* base = out + (((size_t)(k0 >> 6) * nbN + nb) * 256 + rg) * 64 + kh * 32;
  #pragma unroll
  for (int p4 = 0; p4 < 4; ++p4) {
    const int c = (kh * 4 + p4) ^ x;      // source k-chunk for stored position
    bf16x8 o;
    #pragma unroll
    for (int j = 0; j < 8; ++j) o[j] = (bf16_t)tile[c * 8 + j][n];
    *(bf16x8*)(base + (p4 << 3)) = o;
  }
}

// ---------------- LayerNorm, one WAVE per row ----------------
// MODE 0: plain LN(x).  MODE 1: x += pa_z0 + pa_z1 (bf16 slabs), then LN.
// MODE 2: x = wte[id] + wpe[t] (embedding, layer 0), then LN.
template <int MODE>
__global__ __launch_bounds__(256) void ln_kernel(float* __restrict__ x,
                                                 const bf16_t* __restrict__ pa,
                                                 const float* __restrict__ w,
                                                 const float* __restrict__ b,
                                                 bf16_t* __restrict__ out,
                                                 const int* __restrict__ ids,
                                                 const float* __restrict__ wte,
                                                 const float* __restrict__ wpe) {
  const int lane = threadIdx.x & 63, wv = threadIdx.x >> 6;
  const int row = blockIdx.x * 4 + wv;
  float* xr = x + (size_t)row * DM;
  const int c = lane * 4;
  float4 v0, v1, v2;
  if (MODE == 2) {
    const int tt = row & (TT - 1);
    const int id = ids[row];
    const float* wt = wte + (size_t)id * DM;
    const float* wp = wpe + (size_t)tt * DM;
    #pragma unroll
    for (int i = 0; i < 3; ++i) {
      const int cc = c + i * 256;
      float4 a = *(const float4*)&wt[cc];
      float4 bb = *(const float4*)&wp[cc];
      a.x += bb.x; a.y += bb.y; a.z += bb.z; a.w += bb.w;
      float4& v = i == 0 ? v0 : (i == 1 ? v1 : v2);
      v = a;
      *(float4*)&xr[cc] = v;
    }
  } else {
    v0 = *(const float4*)&xr[c];
    v1 = *(const float4*)&xr[c + 256];
    v2 = *(const float4*)&xr[c + 512];
  }
  if (MODE == 1) {
    const bf16_t* p0 = pa + (size_t)row * DM;
    const bf16_t* p1 = pa + (size_t)MR * DM + (size_t)row * DM;
    #pragma unroll
    for (int i = 0; i < 3; ++i) {
      const int cc = c + i * 256;
      bf16x4 a = *(const bf16x4*)&p0[cc];
      bf16x4 bb = *(const bf16x4*)&p1[cc];
      float4& v = i == 0 ? v0 : (i == 1 ? v1 : v2);
      v.x += (float)a[0] + (float)bb[0];
      v.y += (float)a[1] + (float)bb[1];
      v.z += (float)a[2] + (float)bb[2];
      v.w += (float)a[3] + (float)bb[3];
      *(float4*)&xr[cc] = v;
    }
  }
  float s = v0.x + v0.y + v0.z + v0.w + v1.x + v1.y + v1.z + v1.w
          + v2.x + v2.y + v2.z + v2.w;
  #pragma unroll
  for (int off = 32; off > 0; off >>= 1) s += __shfl_xor(s, off);
  const float mean = s * (1.0f / DM);
  float q = 0.0f;
  q += (v0.x-mean)*(v0.x-mean) + (v0.y-mean)*(v0.y-mean) + (v0.z-mean)*(v0.z-mean) + (v0.w-mean)*(v0.w-mean);
  q += (v1.x-mean)*(v1.x-mean) + (v1.y-mean)*(v1.y-mean) + (v1.z-mean)*(v1.z-mean) + (v1.w-mean)*(v1.w-mean);
  q += (v2.x-mean)*(v2.x-mean) + (v2.y-mean)*(v2.y-mean) + (v2.z-mean)*(v2.z-mean) + (v2.w-mean)*(v2.w-mean);
  #pragma unroll
  for (int off = 32; off > 0; off >>= 1) q += __shfl_xor(q, off);
  const float rs = rsqrtf(q * (1.0f / DM) + 1e-5f);
  bf16_t* o = out + (size_t)row * DM;
  #pragma unroll
  for (int i = 0; i < 3; ++i) {
    const int cc = c + i * 256;
    float4 vv = i == 0 ? v0 : (i == 1 ? v1 : v2);
    float4 ww = *(const float4*)&w[cc];
    float4 bb = *(const float4*)&b[cc];
    bf16x4 ob;
    ob[0] = (bf16_t)((vv.x - mean) * rs * ww.x + bb.x);
    ob[1] = (bf16_t)((vv.y - mean) * rs * ww.y + bb.y);
    ob[2] = (bf16_t)((vv.z - mean) * rs * ww.z + bb.z);
    ob[3] = (bf16_t)((vv.w - mean) * rs * ww.w + bb.w);
    *(bf16x4*)&o[cc] = ob;
  }
}

// =====================================================================
// 128x128 GEMM, 4 waves (2Mx2N), BK=64, SINGLE-buffered 32 KB LDS,
// launch_bounds(256,3) -> 3 blocks/CU (round-14 verified regime; (256,4)
// spilled: VGPR crushed to 64, 29MB scratch traffic, +17% — reverted).
// Both A-halves in regs (af[2][..]) -> 16 ds_read_b128/tile, no B re-read.
// SPLITK>1: blockIdx.z covers k-range. EPI2/ATOM0 -> bf16 partial store.
// =====================================================================
#define OFF(MAT, H) ((((MAT)*2) + (H)) * 4096)

#define STAGE(MAT, H, T) do {                                                   \
    const int _r0 = tid >> 3, _r1 = _r0 + 32, _c = tid & 7;                     \
    if ((MAT) == 0) {                                                           \
      const bf16_t* _g0 = A + (size_t)(m0 + (H)*32 + (_r0 & 31)) * Kstride      \
              + (T)*64 + ((_c ^ (_r0 & 7)) << 3);                               \
      const bf16_t* _g1 = A + (size_t)(m0 + 64 + (H)*32 + (_r1 & 31)) * Kstride \
              + (T)*64 + ((_c ^ (_r1 & 7)) << 3);                               \
      gload_lds16(_g0, &lds[OFF(0, H) + (w << 9)]);                             \
      gload_lds16(_g1, &lds[OFF(0, H) + 2048 + (w << 9)]);                      \
    } else {                                                                    \
      const int _gr0 = nboff + (H)*32 + (_r0 & 31);                             \
      const int _gr1 = nboff + 64 + (H)*32 + (_r1 & 31);                        \
      const bf16_t* _bb = BTB + (((size_t)(T) * nbN + nb256) << 14);            \
      gload_lds16(_bb + (_gr0 << 6) + (_c << 3), &lds[OFF(1, H) + (w << 9)]);        \
      gload_lds16(_bb + (_gr1 << 6) + (_c << 3), &lds[OFF(1, H) + 2048 + (w << 9)]); \
    }                                                                           \
  } while (0)

#define RD_A(MH) do {                                                           \
    _Pragma("unroll") for (int _mf = 0; _mf < 2; ++_mf) {                       \
      const int _lr = wr * 32 + _mf * 16 + l15;                                 \
      const int _x = _lr & 7;                                                   \
      af[MH][_mf][0] = *(const bf16x8*)&lds[OFF(0,MH) + _lr*64 + ((l4 ^ _x) << 3)];      \
      af[MH][_mf][1] = *(const bf16x8*)&lds[OFF(0,MH) + _lr*64 + (((4+l4) ^ _x) << 3)];  \
    } } while (0)

#define RD_B(NH) do {                                                           \
    _Pragma("unroll") for (int _nf = 0; _nf < 2; ++_nf) {                       \
      const int _lr = wc * 32 + _nf * 16 + l15;                                 \
      const int _x = _lr & 7;                                                   \
      bfr[_nf][0] = *(const bf16x8*)&lds[OFF(1,NH) + _lr*64 + ((l4 ^ _x) << 3)];         \
      bfr[_nf][1] = *(const bf16x8*)&lds[OFF(1,NH) + _lr*64 + (((4+l4) ^ _x) << 3)];     \
    } } while (0)

#define MM(MH, NH) do {                                                         \
    __builtin_amdgcn_s_setprio(1);                                              \
    _Pragma("unroll") for (int _ks = 0; _ks < 2; ++_ks)                         \
      _Pragma("unroll") for (int _mf = 0; _mf < 2; ++_mf)                       \
        _Pragma("unroll") for (int _nf = 0; _nf < 2; ++_nf)                     \
          acc[(MH)*2+_mf][(NH)*2+_nf] = __builtin_amdgcn_mfma_f32_16x16x32_bf16(\
              af[MH][_mf][_ks], bfr[_nf][_ks], acc[(MH)*2+_mf][(NH)*2+_nf], 0,0,0); \
    __builtin_amdgcn_s_setprio(0);                                              \
  } while (0)

// EPI: 0 = +bias -> bf16 ; 1 = +bias, tanh-approx GELU -> bf16 ; 2 = resid (see above)
template <int EPI, int SPLITK, int ATOM>
__global__ __launch_bounds__(256, 3) void gemm8(const bf16_t* __restrict__ A,
                                                const bf16_t* __restrict__ BTB,
                                                const float* __restrict__ bias,
                                                bf16_t* __restrict__ outb,
                                                float* __restrict__ resid,
                                                int Ndim, int Kdim, int Kstride, int nbN) {
  __shared__ bf16_t lds[16384];   // 32 KB single-buffered -> 3 blocks/CU
  const int tid = threadIdx.x, lane = tid & 63, w = tid >> 6;
  const int wr = w >> 1, wc = w & 1;
  const int l15 = lane & 15, l4 = lane >> 4;
  const int zz = (SPLITK > 1) ? blockIdx.z : 0;
  A += (size_t)zz * Kdim;
  BTB += ((size_t)zz * (Kdim >> 6) * nbN) << 14;

  // T1: bijective XCD-aware tile swizzle (m204). All grids here are %8==0.
  const unsigned nwg = gridDim.x * gridDim.y;
  const unsigned orig = blockIdx.y * gridDim.x + blockIdx.x;
  const unsigned q8 = nwg >> 3;
  const unsigned wg = (orig & 7) * q8 + (orig >> 3);
  const int m0 = (int)(wg / gridDim.x) * 128;
  const int n0 = (int)(wg % gridDim.x) * 128;
  const int nb256 = n0 >> 8, nboff = n0 & 255;   // 128-aligned -> nboff in {0,128}
  const int nT = Kdim >> 6;

  f32x4 acc[4][4] = {};
  bf16x8 af[2][2][2], bfr[2][2];

  for (int t = 0; t < nT; ++t) {
    __syncthreads();                 // previous tile's reads complete
    STAGE(0, 0, t); STAGE(1, 0, t); STAGE(0, 1, t); STAGE(1, 1, t);
    __syncthreads();                 // vmcnt(0) drain -> tile visible (TLP covers)
    RD_A(0); RD_A(1); RD_B(0);
    MM(0, 0); MM(1, 0);
    RD_B(1);
    MM(0, 1); MM(1, 1);
  }

  // epilogue: wave tile 64x64; acc[i][j] -> rows i*16, cols j*16
  #pragma unroll
  for (int mf = 0; mf < 4; ++mf) {
    #pragma unroll
    for (int nf = 0; nf < 4; ++nf) {
      const int col = n0 + wc * 64 + nf * 16 + l15;
      const float bv = (SPLITK == 1 || zz == 0) ? bias[col] : 0.0f;
      #pragma unroll
      for (int r = 0; r < 4; ++r) {
        const int row = m0 + wr * 64 + mf * 16 + l4 * 4 + r;
        float v = acc[mf][nf][r] + bv;
        if (EPI == 1) {
          const float z2 = 1.5957692f * v + 0.07135481f * v * v * v;
          v = v / (1.0f + __expf(-z2));
        }
        if (EPI == 2) {
          if (SPLITK > 1 && ATOM == 0) {
            outb[(size_t)zz * MR * Ndim + (size_t)row * Ndim + col] = (bf16_t)v;
          } else if (SPLITK > 1) {
            unsafeAtomicAdd(&resid[(size_t)row * Ndim + col], v);
          } else {
            resid[(size_t)row * Ndim + col] += v;
          }
        } else {
          outb[(size_t)row * Ndim + col] = (bf16_t)v;
        }
      }
    }
  }
}

// ---------------- fused flash attention (unchanged) ----------------
__global__ __launch_bounds__(512, 4) void attn_kernel(const bf16_t* __restrict__ qkv,
                                                      bf16_t* __restrict__ y) {
  const int qt = blockIdx.x, hh = blockIdx.y, bb = blockIdx.z;
  const int tid = threadIdx.x, lane = tid & 63, w = tid >> 6;
  const int l31 = lane & 31, hiL = lane >> 5;

  __shared__ bf16_t smem[18432];
  bf16_t* Kbuf = smem;
  bf16_t* Vbuf = smem + 8192;

  const bf16_t* kb = qkv + (size_t)(bb * TT) * D3 + DM + hh * 64;
  const bf16_t* vb = qkv + (size_t)(bb * TT) * D3 + 2 * DM + hh * 64;

  const bf16_t* qptr = qkv + (size_t)(bb * TT + qt * 256 + w * 32 + l31) * D3 + hh * 64 + hiL * 8;
  bf16x8 qreg[4];
  #pragma unroll
  for (int ks = 0; ks < 4; ++ks) {
    bf16x8 v = *(const bf16x8*)(qptr + ks * 16);
    #pragma unroll
    for (int j = 0; j < 8; ++j) qreg[ks][j] = (bf16_t)((float)v[j] * 0.125f);
  }

  const int sr = tid >> 3, sc = tid & 7;
  #define ATTN_STAGE(KT, BUF)                                                     \
    {                                                                             \
      gload_lds16(kb + (size_t)((KT) * 64 + sr) * D3 + ((sc ^ (sr & 7)) * 8),     \
                  Kbuf + (BUF) * 4096 + (w << 9));                                \
      bf16x8 tv;                                                                  \
      _Pragma("unroll")                                                           \
      for (int j = 0; j < 8; ++j) tv[j] = vb[(size_t)((KT) * 64 + w * 8 + j) * D3 + lane]; \
      *(bf16x8*)&Vbuf[(BUF) * 4096 + lane * 64 + ((w ^ (lane & 7)) << 3)] = tv;   \
    }

  ATTN_STAGE(0, 0);

  f32x16 o0 = 0.0f, o1 = 0.0f;
  float m = -INFINITY, l = 0.0f;

  for (int kt = 0; kt < 8; ++kt) {
    __syncthreads();
    if (kt < 7) ATTN_STAGE(kt + 1, (kt + 1) & 1);

    const bf16_t* Kb = Kbuf + (kt & 1) * 4096;
    const bf16_t* Vb = Vbuf + (kt & 1) * 4096;

    f32x16 st0 = 0.0f, st1 = 0.0f;
    #pragma unroll
    for (int ks = 0; ks < 4; ++ks) {
      const int ch = (ks * 2 + hiL) ^ (l31 & 7);
      bf16x8 kf0 = *(const bf16x8*)&Kb[l31 * 64 + ch * 8];
      bf16x8 kf1 = *(const bf16x8*)&Kb[(32 + l31) * 64 + ch * 8];
      st0 = __builtin_amdgcn_mfma_f32_32x32x16_bf16(kf0, qreg[ks], st0, 0, 0, 0);
      st1 = __builtin_amdgcn_mfma_f32_32x32x16_bf16(kf1, qreg[ks], st1, 0, 0, 0);
    }

    float tm = fmaxf(st0[0], st1[0]);
    #pragma unroll
    for (int i = 1; i < 16; ++i) tm = fmaxf(tm, fmaxf(st0[i], st1[i]));
    tm = fmaxf(tm, __shfl_xor(tm, 32));
    const float mnew = fmaxf(m, tm);
    const float al = __expf(m - mnew);
    #pragma unroll
    for (int i = 0; i < 16; ++i) st0[i] = __expf(st0[i] - mnew);
    #pragma unroll
    for (int i = 0; i < 16; ++i) st1[i] = __expf(st1[i] - mnew);
    float ps = 0.0f;
    #pragma unroll
    for (int i = 0; i < 16; ++i) ps += st0[i] + st1[i];
    ps += __shfl_xor(ps, 32);
    l = l * al + ps;
    m = mnew;
    #pragma unroll
    for (int i = 0; i < 16; ++i) { o0[i] *= al; o1[i] *= al; }

    #pragma unroll
    for (int g = 0; g < 2; ++g) {
      unsigned u0, u1, u2, u3, u4, u5, u6, u7;
      if (g == 0) {
        u0 = pkbf(st0[0], st0[1]);   u1 = pkbf(st0[2], st0[3]);
        u2 = pkbf(st0[4], st0[5]);   u3 = pkbf(st0[6], st0[7]);
        u4 = pkbf(st0[8], st0[9]);   u5 = pkbf(st0[10], st0[11]);
        u6 = pkbf(st0[12], st0[13]); u7 = pkbf(st0[14], st0[15]);
      } else {
        u0 = pkbf(st1[0], st1[1]);   u1 = pkbf(st1[2], st1[3]);
        u2 = pkbf(st1[4], st1[5]);   u3 = pkbf(st1[6], st1[7]);
        u4 = pkbf(st1[8], st1[9]);   u5 = pkbf(st1[10], st1[11]);
        u6 = pkbf(st1[12], st1[13]); u7 = pkbf(st1[14], st1[15]);
      }
      #pragma unroll
      for (int ks2 = 0; ks2 < 2; ++ks2) {
        const unsigned a0 = ks2 ? u4 : u0, a1 = ks2 ? u5 : u1;
        const unsigned a2 = ks2 ? u6 : u2, a3 = ks2 ? u7 : u3;
        const unsigned own0 = hiL ? a2 : a0, own1 = hiL ? a3 : a1;
        const unsigned snd0 = hiL ? a0 : a2, snd1 = hiL ? a1 : a3;
        const unsigned rcv0 = (unsigned)__shfl_xor((int)snd0, 32);
        const unsigned rcv1 = (unsigned)__shfl_xor((int)snd1, 32);
        u32x4 fw;
        fw[0] = hiL ? rcv0 : own0;
        fw[1] = hiL ? rcv1 : own1;
        fw[2] = hiL ? own0 : rcv0;
        fw[3] = hiL ? own1 : rcv1;
        const bf16x8 pa = __builtin_bit_cast(bf16x8, fw);
        const int chv = (g * 4 + ks2 * 2 + hiL) ^ (l31 & 7);
        bf16x8 vf0 = *(const bf16x8*)&Vb[l31 * 64 + chv * 8];
        bf16x8 vf1 = *(const bf16x8*)&Vb[(32 + l31) * 64 + chv * 8];
        o0 = __builtin_amdgcn_mfma_f32_32x32x16_bf16(vf0, pa, o0, 0, 0, 0);
        o1 = __builtin_amdgcn_mfma_f32_32x32x16_bf16(vf1, pa, o1, 0, 0, 0);
      }
    }
  }

  __syncthreads();
  const float rl = 1.0f / l;
  bf16_t* Ob = smem;
  #pragma unroll
  for (int reg = 0; reg < 16; ++reg) {
    const int drow = (reg & 3) + 8 * (reg >> 2) + 4 * hiL;
    Ob[(w * 32 + l31) * 72 + drow]      = (bf16_t)(o0[reg] * rl);
    Ob[(w * 32 + l31) * 72 + 32 + drow] = (bf16_t)(o1[reg] * rl);
  }
  __syncthreads();
  const int qrow = tid >> 1, half = tid & 1;
  bf16_t* yp = y + (size_t)(bb * TT + qt * 256 + qrow) * DM + hh * 64 + half * 32;
  const bf16_t* obp = &Ob[qrow * 72 + half * 32];
  *(bf16x8*)(yp)      = *(const bf16x8*)(obp);
  *(bf16x8*)(yp + 8)  = *(const bf16x8*)(obp + 8);
  *(bf16x8*)(yp + 16) = *(const bf16x8*)(obp + 16);
  *(bf16x8*)(yp + 24) = *(const bf16x8*)(obp + 24);
  #undef ATTN_STAGE
}

// ---------------- final LN (CLS) + dense + tanh -> pooled (MERGE: + bf16 partials) ----------------
template <int MERGE>
__global__ __launch_bounds__(256) void pooled_kernel(const float* __restrict__ x,
                                                     const bf16_t* __restrict__ pa,
                                                     const float* __restrict__ lnw,
                                                     const float* __restrict__ lnb,
                                                     const float* __restrict__ dw,
                                                     const float* __restrict__ db,
                                                     float* __restrict__ pooled) {
  const int bb = blockIdx.y, tid = threadIdx.x;
  const int lane = tid & 63, wv = tid >> 6;
  const size_t rb = (size_t)(bb * TT) * DM;
  const float* xr = x + rb;
  float v0 = xr[tid], v1 = xr[tid + 256], v2 = xr[tid + 512];
  if (MERGE) {
    const bf16_t* p0 = pa + rb;
    const bf16_t* p1 = pa + (size_t)MR * DM + rb;
    v0 += (float)p0[tid]       + (float)p1[tid];
    v1 += (float)p0[tid + 256] + (float)p1[tid + 256];
    v2 += (float)p0[tid + 512] + (float)p1[tid + 512];
  }
  __shared__ float red[8];
  __shared__ float lx[DM];
  float s = v0 + v1 + v2;
  #pragma unroll
  for (int off = 32; off > 0; off >>= 1) s += __shfl_down(s, off);
  if (lane == 0) red[wv] = s;
  __syncthreads();
  const float mean = (red[0] + red[1] + red[2] + red[3]) * (1.0f / DM);
  const float d0 = v0 - mean, d1 = v1 - mean, d2 = v2 - mean;
  float q = d0 * d0 + d1 * d1 + d2 * d2;
  #pragma unroll
  for (int off = 32; off > 0; off >>= 1) q += __shfl_down(q, off);
  __syncthreads();
  if (lane == 0) red[wv] = q;
  __syncthreads();
  const float var = (red[0] + red[1] + red[2] + red[3]) * (1.0f / DM);
  const float rs = rsqrtf(var + 1e-5f);

  lx[tid]       = d0 * rs * lnw[tid] + lnb[tid];
  lx[tid + 256] = d1 * rs * lnw[tid + 256] + lnb[tid + 256];
  lx[tid + 512] = d2 * rs * lnw[tid + 512] + lnb[tid + 512];
  __syncthreads();

  const int j = blockIdx.x * 64 + (tid >> 2), sl = tid & 3;
  const int k0 = sl * 192;
  float acc = 0.0f;
  #pragma unroll 4
  for (int k = k0; k < k0 + 192; ++k) acc += lx[k] * dw[(size_t)k * DM + j];
  acc += __shfl_xor(acc, 1);
  acc += __shfl_xor(acc, 2);
  if (sl == 0) pooled[bb * DM + j] = tanhf(acc + db[j]);
}

// ---------------- logits ----------------
__global__ void logits_kernel(const float* __restrict__ pooled,
                              const float* __restrict__ hw,
                              const float* __restrict__ hb,
                              float* __restrict__ out) {
  const int tid = threadIdx.x;
  if (tid < 32) {
    const int bb = tid >> 1, c = tid & 1;
    float acc = hb[c];
    for (int k = 0; k < DM; ++k) acc += pooled[bb * DM + k] * hw[k * 2 + c];
    out[bb * 2 + c] = acc;
  }
}

extern "C" void kernel_launch(void* const* d_in, const int* in_sizes, int n_in,
                              void* d_out, int out_size, void* d_ws, size_t ws_size,
                              hipStream_t stream) {
  const int*   ids   = (const int*)d_in[0];
  const float* wte   = (const float*)d_in[3];
  const float* wpe   = (const float*)d_in[4];
  const float* ln1w  = (const float*)d_in[5];
  const float* ln1b  = (const float*)d_in[6];
  const float* wqkv  = (const float*)d_in[7];
  const float* bqkv  = (const float*)d_in[8];
  const float* wo    = (const float*)d_in[9];
  const float* bo    = (const float*)d_in[10];
  const float* ln2w  = (const float*)d_in[11];
  const float* ln2b  = (const float*)d_in[12];
  const float* wfc   = (const float*)d_in[13];
  const float* bfc   = (const float*)d_in[14];
  const float* wproj = (const float*)d_in[15];
  const float* bproj = (const float*)d_in[16];
  const float* lnfw  = (const float*)d_in[17];
  const float* lnfb  = (const float*)d_in[18];
  const float* dw    = (const float*)d_in[19];
  const float* db    = (const float*)d_in[20];
  const float* hw    = (const float*)d_in[21];
  const float* hb    = (const float*)d_in[22];
  float* out = (float*)d_out;

  const size_t NEED_FULLW = 308330496ULL;                 // base + 12-layer weights
  const size_t NEED_SLAB  = NEED_FULLW + 25165824ULL;     // + bf16 proj partial slab
  const int mode = ws_size >= NEED_SLAB ? 2 : (ws_size >= NEED_FULLW ? 1 : 0);
  const bool full = mode >= 1;
  const bool slab = mode == 2;

  char* ws = (char*)d_ws;
  size_t off = 0;
  auto alloc = [&](size_t bytes) -> void* {
    void* p = ws + off;
    off += (bytes + 255) & ~(size_t)255;
    return p;
  };
  float*  x      = (float*)alloc((size_t)MR * DM * 4);
  bf16_t* h      = (bf16_t*)alloc((size_t)MR * DM * 2);
  bf16_t* qkvb   = (bf16_t*)alloc((size_t)MR * D3 * 2);
  bf16_t* yb     = (bf16_t*)alloc((size_t)MR * DM * 2);
  bf16_t* ub     = (bf16_t*)alloc((size_t)MR * D4 * 2);
  float*  pooled = (float*)alloc((size_t)NB * DM * 4);
  const size_t wmul = full ? NL : 1;
  bf16_t* wqkvT  = (bf16_t*)alloc((size_t)D3 * DM * 2 * wmul);
  bf16_t* woT    = (bf16_t*)alloc((size_t)DM * DM * 2 * wmul);
  bf16_t* wfcT   = (bf16_t*)alloc((size_t)D4 * DM * 2 * wmul);
  bf16_t* wprojT = (bf16_t*)alloc((size_t)DM * D4 * 2 * wmul);
  bf16_t* slabP  = slab ? (bf16_t*)alloc((size_t)2 * MR * DM * 2) : nullptr;
  bf16_t* slabW  = (bf16_t*)ub;   // wo partials alias ub (25MB of 50MB; disjoint lifetime)

  if (full) {
    transpose_half<0><<<dim3(288, 1, NL), 256, 0, stream>>>(
        wqkv, wo, wfc, wproj, wqkvT, woT, wfcT, wprojT, 0, 0);
    transpose_half<1><<<dim3(576, 1, NL), 256, 0, stream>>>(
        wqkv, wo, wfc, wproj, wqkvT, woT, wfcT, wprojT, 0, 0);
  }

  for (int l = 0; l < NL; ++l) {
    if (!full) {
      transpose_half<0><<<dim3(288, 1, 1), 256, 0, stream>>>(
          wqkv, wo, wfc, wproj, wqkvT, woT, wfcT, wprojT, l, 1);
      transpose_half<1><<<dim3(576, 1, 1), 256, 0, stream>>>(
          wqkv, wo, wfc, wproj, wqkvT, woT, wfcT, wprojT, l, 1);
    }
    bf16_t* qkvT_l = wqkvT + (full ? (size_t)l * D3 * DM : 0);
    bf16_t* woT_l  = woT   + (full ? (size_t)l * DM * DM : 0);
    bf16_t* fcT_l  = wfcT  + (full ? (size_t)l * D4 * DM : 0);
    bf16_t* prT_l  = wprojT+ (full ? (size_t)l * DM * D4 : 0);

    // ln1: l==0 fuses the embedding; slab mode merges previous layer's proj partials
    if (l == 0)
      ln_kernel<2><<<MR / 4, 256, 0, stream>>>(x, nullptr, ln1w, ln1b, h, ids, wte, wpe);
    else if (slab)
      ln_kernel<1><<<MR / 4, 256, 0, stream>>>(x, slabP, ln1w + l * DM, ln1b + l * DM, h,
                                               nullptr, nullptr, nullptr);
    else
      ln_kernel<0><<<MR / 4, 256, 0, stream>>>(x, nullptr, ln1w + l * DM, ln1b + l * DM, h,
                                               nullptr, nullptr, nullptr);

    gemm8<0, 1, 1><<<dim3(D3 / 128, MR / 128, 1), 256, 0, stream>>>(
        h, qkvT_l, bqkv + (size_t)l * D3, qkvb, nullptr, D3, DM, DM, D3 / 256);
    attn_kernel<<<dim3(TT / 256, NH, NB), 512, 0, stream>>>(qkvb, yb);

    if (slab) {
      gemm8<2, 2, 0><<<dim3(DM / 128, MR / 128, 2), 256, 0, stream>>>(
          yb, woT_l, bo + (size_t)l * DM, slabW, nullptr, DM, DM / 2, DM, DM / 256);
      ln_kernel<1><<<MR / 4, 256, 0, stream>>>(x, slabW, ln2w + l * DM, ln2b + l * DM, h,
                                               nullptr, nullptr, nullptr);
    } else {
      gemm8<2, 2, 1><<<dim3(DM / 128, MR / 128, 2), 256, 0, stream>>>(
          yb, woT_l, bo + (size_t)l * DM, nullptr, x, DM, DM / 2, DM, DM / 256);
      ln_kernel<0><<<MR / 4, 256, 0, stream>>>(x, nullptr, ln2w + l * DM, ln2b + l * DM, h,
                                               nullptr, nullptr, nullptr);
    }

    gemm8<1, 1, 1><<<dim3(D4 / 128, MR / 128, 1), 256, 0, stream>>>(
        h, fcT_l, bfc + (size_t)l * D4, ub, nullptr, D4, DM, DM, D4 / 256);

    if (slab) {
      gemm8<2, 2, 0><<<dim3(DM / 128, MR / 128, 2), 256, 0, stream>>>(
          ub, prT_l, bproj + (size_t)l * DM, slabP, nullptr, DM, D4 / 2, D4, DM / 256);
    } else {
      gemm8<2, 2, 1><<<dim3(DM / 128, MR / 128, 2), 256, 0, stream>>>(
          ub, prT_l, bproj + (size_t)l * DM, nullptr, x, DM, D4 / 2, D4, DM / 256);
    }
  }

  if (slab)
    pooled_kernel<1><<<dim3(12, NB), 256, 0, stream>>>(x, slabP, lnfw, lnfb, dw, db, pooled);
  else
    pooled_kernel<0><<<dim3(12, NB), 256, 0, stream>>>(x, nullptr, lnfw, lnfb, dw, db, pooled);
  logits_kernel<<<1, 64, 0, stream>>>(pooled, hw, hb, out);
}

// Round 17
// 2763.117 us; speedup vs baseline: 1.1990x; 1.0060x over previous
//
#include <hip/hip_runtime.h>
#include <hip/hip_bf16.h>
#include <math.h>

// Problem constants
#define NL 12
#define NH 12
#define DM 768
#define DH 64
#define TT 512
#define NB 16
#define MR (NB*TT)      // 8192 rows
#define D3 (3*DM)       // 2304
#define D4 (4*DM)       // 3072

typedef __bf16 bf16_t;
typedef __attribute__((ext_vector_type(8))) __bf16 bf16x8;
typedef __attribute__((ext_vector_type(4))) __bf16 bf16x4;
typedef __attribute__((ext_vector_type(4))) float f32x4;
typedef __attribute__((ext_vector_type(16))) float f32x16;
typedef __attribute__((ext_vector_type(4))) unsigned int u32x4;

__device__ __forceinline__ void gload_lds16(const void* g, void* l) {
  __builtin_amdgcn_global_load_lds(
      (const __attribute__((address_space(1))) unsigned int*)g,
      (__attribute__((address_space(3))) unsigned int*)l,
      16, 0, 0);
}

__device__ __forceinline__ unsigned pkbf(float a, float b) {
  unsigned short ua = __builtin_bit_cast(unsigned short, (bf16_t)a);
  unsigned short ub = __builtin_bit_cast(unsigned short, (bf16_t)b);
  return (unsigned)ua | ((unsigned)ub << 16);
}

// ---------------- weight transpose + f32->bf16 into BLOCKED layout, 2 dispatches ----------------
template <int HALF>
__global__ __launch_bounds__(256) void transpose_half(
    const float* __restrict__ wqkv, const float* __restrict__ wo,
    const float* __restrict__ wfc, const float* __restrict__ wproj,
    bf16_t* __restrict__ qkvT, bf16_t* __restrict__ woT,
    bf16_t* __restrict__ fcT, bf16_t* __restrict__ projT,
    int l0, int per_layer_out) {
  const int lay = l0 + blockIdx.z;
  int bid = blockIdx.x;
  const float* in; bf16_t* out; int N;
  if (HALF == 0) {
    if (bid < 216) {
      in = wqkv + (size_t)lay * DM * D3;
      out = qkvT + (per_layer_out ? 0 : (size_t)lay * D3 * DM);
      N = D3;
    } else {
      bid -= 216;
      in = wo + (size_t)lay * DM * DM;
      out = woT + (per_layer_out ? 0 : (size_t)lay * DM * DM);
      N = DM;
    }
  } else {
    if (bid < 288) {
      in = wfc + (size_t)lay * DM * D4;
      out = fcT + (per_layer_out ? 0 : (size_t)lay * D4 * DM);
      N = D4;
    } else {
      bid -= 288;
      in = wproj + (size_t)lay * D4 * DM;
      out = projT + (per_layer_out ? 0 : (size_t)lay * DM * D4);
      N = DM;
    }
  }
  const int nx = N >> 7;
  const int n0 = (bid % nx) * 128, k0 = (bid / nx) * 64;
  __shared__ float tile[64][128];   // 32 KB
  const int t = threadIdx.x;
  const int rr = t >> 5, c4 = (t & 31) * 4;
  #pragma unroll
  for (int it = 0; it < 8; ++it) {
    const int row = rr + it * 8;
    f32x4 v = __builtin_nontemporal_load((const f32x4*)&in[(size_t)(k0 + row) * N + n0 + c4]);
    *(f32x4*)&tile[row][c4] = v;
  }
  __syncthreads();
  const int n = t >> 1, kh = t & 1;
  const int rg = (n0 & 255) + n;
  const int nb = n0 >> 8;
  const int nbN = N >> 8;
  const int x = rg & 7;
  bf16_t* base = out + (((size_t)(k0 >> 6) * nbN + nb) * 256 + rg) * 64 + kh * 32;
  #pragma unroll
  for (int p4 = 0; p4 < 4; ++p4) {
    const int c = (kh * 4 + p4) ^ x;      // source k-chunk for stored position
    bf16x8 o;
    #pragma unroll
    for (int j = 0; j < 8; ++j) o[j] = (bf16_t)tile[c * 8 + j][n];
    *(bf16x8*)(base + (p4 << 3)) = o;
  }
}

// ---------------- LayerNorm, one WAVE per row ----------------
// MODE 0: plain LN(x).  MODE 1: x += pa_z0 + pa_z1 (bf16 slabs), then LN.
// MODE 2: x = wte[id] + wpe[t] (embedding, layer 0), then LN.
template <int MODE>
__global__ __launch_bounds__(256) void ln_kernel(float* __restrict__ x,
                                                 const bf16_t* __restrict__ pa,
                                                 const float* __restrict__ w,
                                                 const float* __restrict__ b,
                                                 bf16_t* __restrict__ out,
                                                 const int* __restrict__ ids,
                                                 const float* __restrict__ wte,
                                                 const float* __restrict__ wpe) {
  const int lane = threadIdx.x & 63, wv = threadIdx.x >> 6;
  const int row = blockIdx.x * 4 + wv;
  float* xr = x + (size_t)row * DM;
  const int c = lane * 4;
  float4 v0, v1, v2;
  if (MODE == 2) {
    const int tt = row & (TT - 1);
    const int id = ids[row];
    const float* wt = wte + (size_t)id * DM;
    const float* wp = wpe + (size_t)tt * DM;
    #pragma unroll
    for (int i = 0; i < 3; ++i) {
      const int cc = c + i * 256;
      float4 a = *(const float4*)&wt[cc];
      float4 bb = *(const float4*)&wp[cc];
      a.x += bb.x; a.y += bb.y; a.z += bb.z; a.w += bb.w;
      float4& v = i == 0 ? v0 : (i == 1 ? v1 : v2);
      v = a;
      *(float4*)&xr[cc] = v;
    }
  } else {
    v0 = *(const float4*)&xr[c];
    v1 = *(const float4*)&xr[c + 256];
    v2 = *(const float4*)&xr[c + 512];
  }
  if (MODE == 1) {
    const bf16_t* p0 = pa + (size_t)row * DM;
    const bf16_t* p1 = pa + (size_t)MR * DM + (size_t)row * DM;
    #pragma unroll
    for (int i = 0; i < 3; ++i) {
      const int cc = c + i * 256;
      bf16x4 a = *(const bf16x4*)&p0[cc];
      bf16x4 bb = *(const bf16x4*)&p1[cc];
      float4& v = i == 0 ? v0 : (i == 1 ? v1 : v2);
      v.x += (float)a[0] + (float)bb[0];
      v.y += (float)a[1] + (float)bb[1];
      v.z += (float)a[2] + (float)bb[2];
      v.w += (float)a[3] + (float)bb[3];
      *(float4*)&xr[cc] = v;
    }
  }
  float s = v0.x + v0.y + v0.z + v0.w + v1.x + v1.y + v1.z + v1.w
          + v2.x + v2.y + v2.z + v2.w;
  #pragma unroll
  for (int off = 32; off > 0; off >>= 1) s += __shfl_xor(s, off);
  const float mean = s * (1.0f / DM);
  float q = 0.0f;
  q += (v0.x-mean)*(v0.x-mean) + (v0.y-mean)*(v0.y-mean) + (v0.z-mean)*(v0.z-mean) + (v0.w-mean)*(v0.w-mean);
  q += (v1.x-mean)*(v1.x-mean) + (v1.y-mean)*(v1.y-mean) + (v1.z-mean)*(v1.z-mean) + (v1.w-mean)*(v1.w-mean);
  q += (v2.x-mean)*(v2.x-mean) + (v2.y-mean)*(v2.y-mean) + (v2.z-mean)*(v2.z-mean) + (v2.w-mean)*(v2.w-mean);
  #pragma unroll
  for (int off = 32; off > 0; off >>= 1) q += __shfl_xor(q, off);
  const float rs = rsqrtf(q * (1.0f / DM) + 1e-5f);
  bf16_t* o = out + (size_t)row * DM;
  #pragma unroll
  for (int i = 0; i < 3; ++i) {
    const int cc = c + i * 256;
    float4 vv = i == 0 ? v0 : (i == 1 ? v1 : v2);
    float4 ww = *(const float4*)&w[cc];
    float4 bb = *(const float4*)&b[cc];
    bf16x4 ob;
    ob[0] = (bf16_t)((vv.x - mean) * rs * ww.x + bb.x);
    ob[1] = (bf16_t)((vv.y - mean) * rs * ww.y + bb.y);
    ob[2] = (bf16_t)((vv.z - mean) * rs * ww.z + bb.z);
    ob[3] = (bf16_t)((vv.w - mean) * rs * ww.w + bb.w);
    *(bf16x4*)&o[cc] = ob;
  }
}

// =====================================================================
// 128x128 GEMM, 4 waves (2Mx2N), BK=64, SINGLE-buffered 32 KB LDS,
// launch_bounds(256,3) -> 3 blocks/CU (verified best: cross-block TLP
// covers the staging drain, m114). Both A-halves in regs -> 16
// ds_read_b128/tile, no B re-read. No setprio (T5 null on non-phase-split
// GEMM, m190). SPLITK>1: blockIdx.z covers k-range. EPI2/ATOM0 -> bf16
// partial store (merged by LN).
// =====================================================================
#define OFF(MAT, H) ((((MAT)*2) + (H)) * 4096)

#define STAGE(MAT, H, T) do {                                                   \
    const int _r0 = tid >> 3, _r1 = _r0 + 32, _c = tid & 7;                     \
    if ((MAT) == 0) {                                                           \
      const bf16_t* _g0 = A + (size_t)(m0 + (H)*32 + (_r0 & 31)) * Kstride      \
              + (T)*64 + ((_c ^ (_r0 & 7)) << 3);                               \
      const bf16_t* _g1 = A + (size_t)(m0 + 64 + (H)*32 + (_r1 & 31)) * Kstride \
              + (T)*64 + ((_c ^ (_r1 & 7)) << 3);                               \
      gload_lds16(_g0, &lds[OFF(0, H) + (w << 9)]);                             \
      gload_lds16(_g1, &lds[OFF(0, H) + 2048 + (w << 9)]);                      \
    } else {                                                                    \
      const int _gr0 = nboff + (H)*32 + (_r0 & 31);                             \
      const int _gr1 = nboff + 64 + (H)*32 + (_r1 & 31);                        \
      const bf16_t* _bb = BTB + (((size_t)(T) * nbN + nb256) << 14);            \
      gload_lds16(_bb + (_gr0 << 6) + (_c << 3), &lds[OFF(1, H) + (w << 9)]);        \
      gload_lds16(_bb + (_gr1 << 6) + (_c << 3), &lds[OFF(1, H) + 2048 + (w << 9)]); \
    }                                                                           \
  } while (0)

#define RD_A(MH) do {                                                           \
    _Pragma("unroll") for (int _mf = 0; _mf < 2; ++_mf) {                       \
      const int _lr = wr * 32 + _mf * 16 + l15;                                 \
      const int _x = _lr & 7;                                                   \
      af[MH][_mf][0] = *(const bf16x8*)&lds[OFF(0,MH) + _lr*64 + ((l4 ^ _x) << 3)];      \
      af[MH][_mf][1] = *(const bf16x8*)&lds[OFF(0,MH) + _lr*64 + (((4+l4) ^ _x) << 3)];  \
    } } while (0)

#define RD_B(NH) do {                                                           \
    _Pragma("unroll") for (int _nf = 0; _nf < 2; ++_nf) {                       \
      const int _lr = wc * 32 + _nf * 16 + l15;                                 \
      const int _x = _lr & 7;                                                   \
      bfr[_nf][0] = *(const bf16x8*)&lds[OFF(1,NH) + _lr*64 + ((l4 ^ _x) << 3)];         \
      bfr[_nf][1] = *(const bf16x8*)&lds[OFF(1,NH) + _lr*64 + (((4+l4) ^ _x) << 3)];     \
    } } while (0)

#define MM(MH, NH) do {                                                         \
    _Pragma("unroll") for (int _ks = 0; _ks < 2; ++_ks)                         \
      _Pragma("unroll") for (int _mf = 0; _mf < 2; ++_mf)                       \
        _Pragma("unroll") for (int _nf = 0; _nf < 2; ++_nf)                     \
          acc[(MH)*2+_mf][(NH)*2+_nf] = __builtin_amdgcn_mfma_f32_16x16x32_bf16(\
              af[MH][_mf][_ks], bfr[_nf][_ks], acc[(MH)*2+_mf][(NH)*2+_nf], 0,0,0); \
  } while (0)

// EPI: 0 = +bias -> bf16 ; 1 = +bias, tanh-approx GELU -> bf16 ; 2 = resid (see above)
template <int EPI, int SPLITK, int ATOM>
__global__ __launch_bounds__(256, 3) void gemm8(const bf16_t* __restrict__ A,
                                                const bf16_t* __restrict__ BTB,
                                                const float* __restrict__ bias,
                                                bf16_t* __restrict__ outb,
                                                float* __restrict__ resid,
                                                int Ndim, int Kdim, int Kstride, int nbN) {
  __shared__ bf16_t lds[16384];   // 32 KB single-buffered -> 3 blocks/CU
  const int tid = threadIdx.x, lane = tid & 63, w = tid >> 6;
  const int wr = w >> 1, wc = w & 1;
  const int l15 = lane & 15, l4 = lane >> 4;
  const int zz = (SPLITK > 1) ? blockIdx.z : 0;
  A += (size_t)zz * Kdim;
  BTB += ((size_t)zz * (Kdim >> 6) * nbN) << 14;

  // T1: bijective XCD-aware tile swizzle (m204). All grids here are %8==0.
  const unsigned nwg = gridDim.x * gridDim.y;
  const unsigned orig = blockIdx.y * gridDim.x + blockIdx.x;
  const unsigned q8 = nwg >> 3;
  const unsigned wg = (orig & 7) * q8 + (orig >> 3);
  const int m0 = (int)(wg / gridDim.x) * 128;
  const int n0 = (int)(wg % gridDim.x) * 128;
  const int nb256 = n0 >> 8, nboff = n0 & 255;   // 128-aligned -> nboff in {0,128}
  const int nT = Kdim >> 6;

  f32x4 acc[4][4] = {};
  bf16x8 af[2][2][2], bfr[2][2];

  for (int t = 0; t < nT; ++t) {
    __syncthreads();                 // previous tile's reads complete
    STAGE(0, 0, t); STAGE(1, 0, t); STAGE(0, 1, t); STAGE(1, 1, t);
    __syncthreads();                 // vmcnt(0) drain -> tile visible (TLP covers)
    RD_A(0); RD_A(1); RD_B(0);
    MM(0, 0); MM(1, 0);
    RD_B(1);
    MM(0, 1); MM(1, 1);
  }

  // epilogue: wave tile 64x64; acc[i][j] -> rows i*16, cols j*16
  #pragma unroll
  for (int mf = 0; mf < 4; ++mf) {
    #pragma unroll
    for (int nf = 0; nf < 4; ++nf) {
      const int col = n0 + wc * 64 + nf * 16 + l15;
      const float bv = (SPLITK == 1 || zz == 0) ? bias[col] : 0.0f;
      #pragma unroll
      for (int r = 0; r < 4; ++r) {
        const int row = m0 + wr * 64 + mf * 16 + l4 * 4 + r;
        float v = acc[mf][nf][r] + bv;
        if (EPI == 1) {
          const float z2 = 1.5957692f * v + 0.07135481f * v * v * v;
          v = v / (1.0f + __expf(-z2));
        }
        if (EPI == 2) {
          if (SPLITK > 1 && ATOM == 0) {
            outb[(size_t)zz * MR * Ndim + (size_t)row * Ndim + col] = (bf16_t)v;
          } else if (SPLITK > 1) {
            unsafeAtomicAdd(&resid[(size_t)row * Ndim + col], v);
          } else {
            resid[(size_t)row * Ndim + col] += v;
          }
        } else {
          outb[(size_t)row * Ndim + col] = (bf16_t)v;
        }
      }
    }
  }
}

// ---------------- fused flash attention (unchanged; setprio kept — m191 positive on attn) ----------------
__global__ __launch_bounds__(512, 4) void attn_kernel(const bf16_t* __restrict__ qkv,
                                                      bf16_t* __restrict__ y) {
  const int qt = blockIdx.x, hh = blockIdx.y, bb = blockIdx.z;
  const int tid = threadIdx.x, lane = tid & 63, w = tid >> 6;
  const int l31 = lane & 31, hiL = lane >> 5;

  __shared__ bf16_t smem[18432];
  bf16_t* Kbuf = smem;
  bf16_t* Vbuf = smem + 8192;

  const bf16_t* kb = qkv + (size_t)(bb * TT) * D3 + DM + hh * 64;
  const bf16_t* vb = qkv + (size_t)(bb * TT) * D3 + 2 * DM + hh * 64;

  const bf16_t* qptr = qkv + (size_t)(bb * TT + qt * 256 + w * 32 + l31) * D3 + hh * 64 + hiL * 8;
  bf16x8 qreg[4];
  #pragma unroll
  for (int ks = 0; ks < 4; ++ks) {
    bf16x8 v = *(const bf16x8*)(qptr + ks * 16);
    #pragma unroll
    for (int j = 0; j < 8; ++j) qreg[ks][j] = (bf16_t)((float)v[j] * 0.125f);
  }

  const int sr = tid >> 3, sc = tid & 7;
  #define ATTN_STAGE(KT, BUF)                                                     \
    {                                                                             \
      gload_lds16(kb + (size_t)((KT) * 64 + sr) * D3 + ((sc ^ (sr & 7)) * 8),     \
                  Kbuf + (BUF) * 4096 + (w << 9));                                \
      bf16x8 tv;                                                                  \
      _Pragma("unroll")                                                           \
      for (int j = 0; j < 8; ++j) tv[j] = vb[(size_t)((KT) * 64 + w * 8 + j) * D3 + lane]; \
      *(bf16x8*)&Vbuf[(BUF) * 4096 + lane * 64 + ((w ^ (lane & 7)) << 3)] = tv;   \
    }

  ATTN_STAGE(0, 0);

  f32x16 o0 = 0.0f, o1 = 0.0f;
  float m = -INFINITY, l = 0.0f;

  for (int kt = 0; kt < 8; ++kt) {
    __syncthreads();
    if (kt < 7) ATTN_STAGE(kt + 1, (kt + 1) & 1);

    const bf16_t* Kb = Kbuf + (kt & 1) * 4096;
    const bf16_t* Vb = Vbuf + (kt & 1) * 4096;

    f32x16 st0 = 0.0f, st1 = 0.0f;
    __builtin_amdgcn_s_setprio(1);
    #pragma unroll
    for (int ks = 0; ks < 4; ++ks) {
      const int ch = (ks * 2 + hiL) ^ (l31 & 7);
      bf16x8 kf0 = *(const bf16x8*)&Kb[l31 * 64 + ch * 8];
      bf16x8 kf1 = *(const bf16x8*)&Kb[(32 + l31) * 64 + ch * 8];
      st0 = __builtin_amdgcn_mfma_f32_32x32x16_bf16(kf0, qreg[ks], st0, 0, 0, 0);
      st1 = __builtin_amdgcn_mfma_f32_32x32x16_bf16(kf1, qreg[ks], st1, 0, 0, 0);
    }
    __builtin_amdgcn_s_setprio(0);

    float tm = fmaxf(st0[0], st1[0]);
    #pragma unroll
    for (int i = 1; i < 16; ++i) tm = fmaxf(tm, fmaxf(st0[i], st1[i]));
    tm = fmaxf(tm, __shfl_xor(tm, 32));
    const float mnew = fmaxf(m, tm);
    const float al = __expf(m - mnew);
    #pragma unroll
    for (int i = 0; i < 16; ++i) st0[i] = __expf(st0[i] - mnew);
    #pragma unroll
    for (int i = 0; i < 16; ++i) st1[i] = __expf(st1[i] - mnew);
    float ps = 0.0f;
    #pragma unroll
    for (int i = 0; i < 16; ++i) ps += st0[i] + st1[i];
    ps += __shfl_xor(ps, 32);
    l = l * al + ps;
    m = mnew;
    #pragma unroll
    for (int i = 0; i < 16; ++i) { o0[i] *= al; o1[i] *= al; }

    #pragma unroll
    for (int g = 0; g < 2; ++g) {
      unsigned u0, u1, u2, u3, u4, u5, u6, u7;
      if (g == 0) {
        u0 = pkbf(st0[0], st0[1]);   u1 = pkbf(st0[2], st0[3]);
        u2 = pkbf(st0[4], st0[5]);   u3 = pkbf(st0[6], st0[7]);
        u4 = pkbf(st0[8], st0[9]);   u5 = pkbf(st0[10], st0[11]);
        u6 = pkbf(st0[12], st0[13]); u7 = pkbf(st0[14], st0[15]);
      } else {
        u0 = pkbf(st1[0], st1[1]);   u1 = pkbf(st1[2], st1[3]);
        u2 = pkbf(st1[4], st1[5]);   u3 = pkbf(st1[6], st1[7]);
        u4 = pkbf(st1[8], st1[9]);   u5 = pkbf(st1[10], st1[11]);
        u6 = pkbf(st1[12], st1[13]); u7 = pkbf(st1[14], st1[15]);
      }
      #pragma unroll
      for (int ks2 = 0; ks2 < 2; ++ks2) {
        const unsigned a0 = ks2 ? u4 : u0, a1 = ks2 ? u5 : u1;
        const unsigned a2 = ks2 ? u6 : u2, a3 = ks2 ? u7 : u3;
        const unsigned own0 = hiL ? a2 : a0, own1 = hiL ? a3 : a1;
        const unsigned snd0 = hiL ? a0 : a2, snd1 = hiL ? a1 : a3;
        const unsigned rcv0 = (unsigned)__shfl_xor((int)snd0, 32);
        const unsigned rcv1 = (unsigned)__shfl_xor((int)snd1, 32);
        u32x4 fw;
        fw[0] = hiL ? rcv0 : own0;
        fw[1] = hiL ? rcv1 : own1;
        fw[2] = hiL ? own0 : rcv0;
        fw[3] = hiL ? own1 : rcv1;
        const bf16x8 pa = __builtin_bit_cast(bf16x8, fw);
        const int chv = (g * 4 + ks2 * 2 + hiL) ^ (l31 & 7);
        bf16x8 vf0 = *(const bf16x8*)&Vb[l31 * 64 + chv * 8];
        bf16x8 vf1 = *(const bf16x8*)&Vb[(32 + l31) * 64 + chv * 8];
        o0 = __builtin_amdgcn_mfma_f32_32x32x16_bf16(vf0, pa, o0, 0, 0, 0);
        o1 = __builtin_amdgcn_mfma_f32_32x32x16_bf16(vf1, pa, o1, 0, 0, 0);
      }
    }
  }

  __syncthreads();
  const float rl = 1.0f / l;
  bf16_t* Ob = smem;
  #pragma unroll
  for (int reg = 0; reg < 16; ++reg) {
    const int drow = (reg & 3) + 8 * (reg >> 2) + 4 * hiL;
    Ob[(w * 32 + l31) * 72 + drow]      = (bf16_t)(o0[reg] * rl);
    Ob[(w * 32 + l31) * 72 + 32 + drow] = (bf16_t)(o1[reg] * rl);
  }
  __syncthreads();
  const int qrow = tid >> 1, half = tid & 1;
  bf16_t* yp = y + (size_t)(bb * TT + qt * 256 + qrow) * DM + hh * 64 + half * 32;
  const bf16_t* obp = &Ob[qrow * 72 + half * 32];
  *(bf16x8*)(yp)      = *(const bf16x8*)(obp);
  *(bf16x8*)(yp + 8)  = *(const bf16x8*)(obp + 8);
  *(bf16x8*)(yp + 16) = *(const bf16x8*)(obp + 16);
  *(bf16x8*)(yp + 24) = *(const bf16x8*)(obp + 24);
  #undef ATTN_STAGE
}

// ---------------- final LN (CLS) + dense + tanh -> pooled (MERGE: + bf16 partials) ----------------
template <int MERGE>
__global__ __launch_bounds__(256) void pooled_kernel(const float* __restrict__ x,
                                                     const bf16_t* __restrict__ pa,
                                                     const float* __restrict__ lnw,
                                                     const float* __restrict__ lnb,
                                                     const float* __restrict__ dw,
                                                     const float* __restrict__ db,
                                                     float* __restrict__ pooled) {
  const int bb = blockIdx.y, tid = threadIdx.x;
  const int lane = tid & 63, wv = tid >> 6;
  const size_t rb = (size_t)(bb * TT) * DM;
  const float* xr = x + rb;
  float v0 = xr[tid], v1 = xr[tid + 256], v2 = xr[tid + 512];
  if (MERGE) {
    const bf16_t* p0 = pa + rb;
    const bf16_t* p1 = pa + (size_t)MR * DM + rb;
    v0 += (float)p0[tid]       + (float)p1[tid];
    v1 += (float)p0[tid + 256] + (float)p1[tid + 256];
    v2 += (float)p0[tid + 512] + (float)p1[tid + 512];
  }
  __shared__ float red[8];
  __shared__ float lx[DM];
  float s = v0 + v1 + v2;
  #pragma unroll
  for (int off = 32; off > 0; off >>= 1) s += __shfl_down(s, off);
  if (lane == 0) red[wv] = s;
  __syncthreads();
  const float mean = (red[0] + red[1] + red[2] + red[3]) * (1.0f / DM);
  const float d0 = v0 - mean, d1 = v1 - mean, d2 = v2 - mean;
  float q = d0 * d0 + d1 * d1 + d2 * d2;
  #pragma unroll
  for (int off = 32; off > 0; off >>= 1) q += __shfl_down(q, off);
  __syncthreads();
  if (lane == 0) red[wv] = q;
  __syncthreads();
  const float var = (red[0] + red[1] + red[2] + red[3]) * (1.0f / DM);
  const float rs = rsqrtf(var + 1e-5f);

  lx[tid]       = d0 * rs * lnw[tid] + lnb[tid];
  lx[tid + 256] = d1 * rs * lnw[tid + 256] + lnb[tid + 256];
  lx[tid + 512] = d2 * rs * lnw[tid + 512] + lnb[tid + 512];
  __syncthreads();

  const int j = blockIdx.x * 64 + (tid >> 2), sl = tid & 3;
  const int k0 = sl * 192;
  float acc = 0.0f;
  #pragma unroll 4
  for (int k = k0; k < k0 + 192; ++k) acc += lx[k] * dw[(size_t)k * DM + j];
  acc += __shfl_xor(acc, 1);
  acc += __shfl_xor(acc, 2);
  if (sl == 0) pooled[bb * DM + j] = tanhf(acc + db[j]);
}

// ---------------- logits ----------------
__global__ void logits_kernel(const float* __restrict__ pooled,
                              const float* __restrict__ hw,
                              const float* __restrict__ hb,
                              float* __restrict__ out) {
  const int tid = threadIdx.x;
  if (tid < 32) {
    const int bb = tid >> 1, c = tid & 1;
    float acc = hb[c];
    for (int k = 0; k < DM; ++k) acc += pooled[bb * DM + k] * hw[k * 2 + c];
    out[bb * 2 + c] = acc;
  }
}

extern "C" void kernel_launch(void* const* d_in, const int* in_sizes, int n_in,
                              void* d_out, int out_size, void* d_ws, size_t ws_size,
                              hipStream_t stream) {
  const int*   ids   = (const int*)d_in[0];
  const float* wte   = (const float*)d_in[3];
  const float* wpe   = (const float*)d_in[4];
  const float* ln1w  = (const float*)d_in[5];
  const float* ln1b  = (const float*)d_in[6];
  const float* wqkv  = (const float*)d_in[7];
  const float* bqkv  = (const float*)d_in[8];
  const float* wo    = (const float*)d_in[9];
  const float* bo    = (const float*)d_in[10];
  const float* ln2w  = (const float*)d_in[11];
  const float* ln2b  = (const float*)d_in[12];
  const float* wfc   = (const float*)d_in[13];
  const float* bfc   = (const float*)d_in[14];
  const float* wproj = (const float*)d_in[15];
  const float* bproj = (const float*)d_in[16];
  const float* lnfw  = (const float*)d_in[17];
  const float* lnfb  = (const float*)d_in[18];
  const float* dw    = (const float*)d_in[19];
  const float* db    = (const float*)d_in[20];
  const float* hw    = (const float*)d_in[21];
  const float* hb    = (const float*)d_in[22];
  float* out = (float*)d_out;

  const size_t NEED_FULLW = 308330496ULL;                 // base + 12-layer weights
  const size_t NEED_SLAB  = NEED_FULLW + 25165824ULL;     // + bf16 proj partial slab
  const int mode = ws_size >= NEED_SLAB ? 2 : (ws_size >= NEED_FULLW ? 1 : 0);
  const bool full = mode >= 1;
  const bool slab = mode == 2;

  char* ws = (char*)d_ws;
  size_t off = 0;
  auto alloc = [&](size_t bytes) -> void* {
    void* p = ws + off;
    off += (bytes + 255) & ~(size_t)255;
    return p;
  };
  float*  x      = (float*)alloc((size_t)MR * DM * 4);
  bf16_t* h      = (bf16_t*)alloc((size_t)MR * DM * 2);
  bf16_t* qkvb   = (bf16_t*)alloc((size_t)MR * D3 * 2);
  bf16_t* yb     = (bf16_t*)alloc((size_t)MR * DM * 2);
  bf16_t* ub     = (bf16_t*)alloc((size_t)MR * D4 * 2);
  float*  pooled = (float*)alloc((size_t)NB * DM * 4);
  const size_t wmul = full ? NL : 1;
  bf16_t* wqkvT  = (bf16_t*)alloc((size_t)D3 * DM * 2 * wmul);
  bf16_t* woT    = (bf16_t*)alloc((size_t)DM * DM * 2 * wmul);
  bf16_t* wfcT   = (bf16_t*)alloc((size_t)D4 * DM * 2 * wmul);
  bf16_t* wprojT = (bf16_t*)alloc((size_t)DM * D4 * 2 * wmul);
  bf16_t* slabP  = slab ? (bf16_t*)alloc((size_t)2 * MR * DM * 2) : nullptr;
  bf16_t* slabW  = (bf16_t*)ub;   // wo partials alias ub (25MB of 50MB; disjoint lifetime)

  if (full) {
    transpose_half<0><<<dim3(288, 1, NL), 256, 0, stream>>>(
        wqkv, wo, wfc, wproj, wqkvT, woT, wfcT, wprojT, 0, 0);
    transpose_half<1><<<dim3(576, 1, NL), 256, 0, stream>>>(
        wqkv, wo, wfc, wproj, wqkvT, woT, wfcT, wprojT, 0, 0);
  }

  for (int l = 0; l < NL; ++l) {
    if (!full) {
      transpose_half<0><<<dim3(288, 1, 1), 256, 0, stream>>>(
          wqkv, wo, wfc, wproj, wqkvT, woT, wfcT, wprojT, l, 1);
      transpose_half<1><<<dim3(576, 1, 1), 256, 0, stream>>>(
          wqkv, wo, wfc, wproj, wqkvT, woT, wfcT, wprojT, l, 1);
    }
    bf16_t* qkvT_l = wqkvT + (full ? (size_t)l * D3 * DM : 0);
    bf16_t* woT_l  = woT   + (full ? (size_t)l * DM * DM : 0);
    bf16_t* fcT_l  = wfcT  + (full ? (size_t)l * D4 * DM : 0);
    bf16_t* prT_l  = wprojT+ (full ? (size_t)l * DM * D4 : 0);

    // ln1: l==0 fuses the embedding; slab mode merges previous layer's proj partials
    if (l == 0)
      ln_kernel<2><<<MR / 4, 256, 0, stream>>>(x, nullptr, ln1w, ln1b, h, ids, wte, wpe);
    else if (slab)
      ln_kernel<1><<<MR / 4, 256, 0, stream>>>(x, slabP, ln1w + l * DM, ln1b + l * DM, h,
                                               nullptr, nullptr, nullptr);
    else
      ln_kernel<0><<<MR / 4, 256, 0, stream>>>(x, nullptr, ln1w + l * DM, ln1b + l * DM, h,
                                               nullptr, nullptr, nullptr);

    gemm8<0, 1, 1><<<dim3(D3 / 128, MR / 128, 1), 256, 0, stream>>>(
        h, qkvT_l, bqkv + (size_t)l * D3, qkvb, nullptr, D3, DM, DM, D3 / 256);
    attn_kernel<<<dim3(TT / 256, NH, NB), 512, 0, stream>>>(qkvb, yb);

    if (slab) {
      gemm8<2, 2, 0><<<dim3(DM / 128, MR / 128, 2), 256, 0, stream>>>(
          yb, woT_l, bo + (size_t)l * DM, slabW, nullptr, DM, DM / 2, DM, DM / 256);
      ln_kernel<1><<<MR / 4, 256, 0, stream>>>(x, slabW, ln2w + l * DM, ln2b + l * DM, h,
                                               nullptr, nullptr, nullptr);
    } else {
      gemm8<2, 2, 1><<<dim3(DM / 128, MR / 128, 2), 256, 0, stream>>>(
          yb, woT_l, bo + (size_t)l * DM, nullptr, x, DM, DM / 2, DM, DM / 256);
      ln_kernel<0><<<MR / 4, 256, 0, stream>>>(x, nullptr, ln2w + l * DM, ln2b + l * DM, h,
                                               nullptr, nullptr, nullptr);
    }

    gemm8<1, 1, 1><<<dim3(D4 / 128, MR / 128, 1), 256, 0, stream>>>(
        h, fcT_l, bfc + (size_t)l * D4, ub, nullptr, D4, DM, DM, D4 / 256);

    if (slab) {
      gemm8<2, 2, 0><<<dim3(DM / 128, MR / 128, 2), 256, 0, stream>>>(
          ub, prT_l, bproj + (size_t)l * DM, slabP, nullptr, DM, D4 / 2, D4, DM / 256);
    } else {
      gemm8<2, 2, 1><<<dim3(DM / 128, MR / 128, 2), 256, 0, stream>>>(
          ub, prT_l, bproj + (size_t)l * DM, nullptr, x, DM, D4 / 2, D4, DM / 256);
    }
  }

  if (slab)
    pooled_kernel<1><<<dim3(12, NB), 256, 0, stream>>>(x, slabP, lnfw, lnfb, dw, db, pooled);
  else
    pooled_kernel<0><<<dim3(12, NB), 256, 0, stream>>>(x, nullptr, lnfw, lnfb, dw, db, pooled);
  logits_kernel<<<1, 64, 0, stream>>>(pooled, hw, hb, out);
}